// Round 1
// baseline (1208.670 us; speedup 1.0000x reference)
//
#include <hip/hip_runtime.h>
#include <hip/hip_bf16.h>
#include <math.h>

#define BN 8
#define AN 15
#define HH 100
#define WW 168
#define HW (HH*WW)           // 16800
#define NPI (AN*HW)          // 252000 scores per image
#define NTOT (BN*NPI)        // 2016000
#define PRE 2000
#define POST 1000
#define CAP 8192             // candidate buffer per image (power of 2 for bitonic)
#define ROWW 32              // u64 words per NMS mask row (2000 bits -> 32 words)
#define RSTRIDE 2048         // padded per-image row stride

typedef unsigned int u32;
typedef unsigned long long u64;

// ---- workspace layout (bytes) ----
#define OFF_HIST   0            // 8*65536*4 = 2097152
#define OFF_CCNT   2097152      // 8*4
#define OFF_THR    2097408      // 8*4
#define OFF_CAND   2098176      // 8*8192*8 = 524288
#define OFF_BOX    2622464      // 8*2048*16 = 262144
#define OFF_SCORE  2884608      // 8*2048*4
#define OFF_VALID  2950144      // 8*2048*4
#define OFF_MASK   3015680      // 8*2048*32*8 = 4194304  (total ~6.9 MB)

__device__ __forceinline__ u32 fmono(float s) {
  u32 u = __float_as_uint(s);
  return (u & 0x80000000u) ? ~u : (u | 0x80000000u);
}
__device__ __forceinline__ float funmono(u32 m) {
  u32 u = (m & 0x80000000u) ? (m ^ 0x80000000u) : ~m;
  return __uint_as_float(u);
}
__device__ __forceinline__ float areaf(float4 bx) {
  return __fmul_rn(__fadd_rn(__fsub_rn(bx.z, bx.x), 1.0f),
                   __fadd_rn(__fsub_rn(bx.w, bx.y), 1.0f));
}

__global__ void zero_kernel(u32* p, int n) {
  int i = blockIdx.x * blockDim.x + threadIdx.x;
  if (i < n) p[i] = 0u;
}

__global__ void hist_kernel(const float* __restrict__ cls, u32* __restrict__ hist) {
  int tid = blockIdx.x * blockDim.x + threadIdx.x;
  if (tid >= NTOT) return;
  int b = tid / NPI;
  u32 m = fmono(cls[tid]);
  atomicAdd(&hist[(b << 16) + (m >> 16)], 1u);
}

__global__ __launch_bounds__(1024) void thresh_kernel(const u32* __restrict__ hist,
                                                      u32* __restrict__ thr) {
  int b = blockIdx.x;
  int t = threadIdx.x;
  __shared__ u32 seg[1024];
  const u32* hb = hist + (b << 16);
  u32 s = 0;
  for (int k = 0; k < 64; ++k) s += hb[t * 64 + k];
  seg[t] = s;
  __syncthreads();
  if (t == 0) {
    u32 acc = 0;
    int sgi = 1023;
    for (; sgi >= 0; --sgi) {
      if (acc + seg[sgi] >= (u32)PRE) break;
      acc += seg[sgi];
    }
    u32 T = 0;
    if (sgi >= 0) {
      u32 a2 = acc;
      T = (u32)(sgi * 64);
      for (int k = 63; k >= 0; --k) {
        a2 += hb[sgi * 64 + k];
        if (a2 >= (u32)PRE) { T = (u32)(sgi * 64 + k); break; }
      }
    }
    thr[b] = T;
  }
}

__global__ void gather_kernel(const float* __restrict__ cls, const u32* __restrict__ thr,
                              u32* __restrict__ ccnt, u64* __restrict__ cand) {
  int tid = blockIdx.x * blockDim.x + threadIdx.x;
  if (tid >= NTOT) return;
  int b = tid / NPI;
  int r = tid - b * NPI;
  u32 m = fmono(cls[tid]);
  if ((m >> 16) >= thr[b]) {
    u32 pos = atomicAdd(&ccnt[b], 1u);
    if (pos < CAP) {
      int a  = r / HW;
      int hw = r - a * HW;
      u32 i  = (u32)(hw * AN + a);   // transposed flat index (h*W + w)*A + a
      cand[b * CAP + pos] = ((u64)m << 32) | (u32)(~i);
    }
  }
}

__global__ __launch_bounds__(1024) void sort_transform_kernel(
    const u64* __restrict__ cand, const u32* __restrict__ ccnt,
    const float* __restrict__ bbox, const float* __restrict__ iminfo,
    const float* __restrict__ anch,
    float4* __restrict__ boxes, float* __restrict__ scores, int* __restrict__ valid) {
  __shared__ u64 keys[CAP];   // 64 KB
  int b = blockIdx.x;
  int t = threadIdx.x;
  u32 cnt = ccnt[b];
  if (cnt > CAP) cnt = CAP;
  for (int q = t; q < CAP; q += 1024) keys[q] = (q < (int)cnt) ? cand[b * CAP + q] : 0ULL;
  __syncthreads();
  // bitonic sort, descending
  for (u32 k = 2; k <= CAP; k <<= 1) {
    for (u32 j = k >> 1; j > 0; j >>= 1) {
      for (int p = 0; p < CAP / 2 / 1024; ++p) {
        u32 idx = (u32)t + (u32)p * 1024u;           // 0..4095
        u32 base = ((idx & ~(j - 1)) << 1) | (idx & (j - 1));
        u32 partner = base + j;
        bool up = ((base & k) == 0);
        u64 A = keys[base], B = keys[partner];
        bool sw = up ? (A < B) : (A > B);
        if (sw) { keys[base] = B; keys[partner] = A; }
      }
      __syncthreads();
    }
  }
  // transform the top PRE
  float im_h = iminfo[b * 3 + 0], im_w = iminfo[b * 3 + 1], im_s = iminfo[b * 3 + 2];
  float wmax = __fsub_rn(im_w, 1.0f), hmax = __fsub_rn(im_h, 1.0f);
  float msz = __fmul_rn(0.0f, im_s);
  const float BCLIP = (float)4.135166556742356;  // log(1000/16)
  for (int q = t; q < PRE; q += 1024) {
    u64 key = keys[q];
    u32 i = ~((u32)key);
    float sc = funmono((u32)(key >> 32));
    int a = (int)(i % AN);
    int pp = (int)(i / AN);
    int w = pp % WW;
    int h = pp / WW;
    float sx = (float)(w * 8), sy = (float)(h * 8);
    float ax1 = __fadd_rn(anch[a * 4 + 0], sx);
    float ay1 = __fadd_rn(anch[a * 4 + 1], sy);
    float ax2 = __fadd_rn(anch[a * 4 + 2], sx);
    float ay2 = __fadd_rn(anch[a * 4 + 3], sy);
    float wsA = __fadd_rn(__fsub_rn(ax2, ax1), 1.0f);
    float hsA = __fadd_rn(__fsub_rn(ay2, ay1), 1.0f);
    float cx = __fadd_rn(ax1, __fmul_rn(0.5f, wsA));
    float cy = __fadd_rn(ay1, __fmul_rn(0.5f, hsA));
    const float* dp = bbox + ((size_t)b * (4 * AN) + 4 * a) * HW + (size_t)h * WW + w;
    float dx = dp[0], dy = dp[HW], dwv = dp[2 * HW], dhv = dp[3 * HW];
    dwv = fminf(dwv, BCLIP);
    dhv = fminf(dhv, BCLIP);
    float pcx = __fadd_rn(__fmul_rn(dx, wsA), cx);
    float pcy = __fadd_rn(__fmul_rn(dy, hsA), cy);
    float pw = __fmul_rn((float)exp((double)dwv), wsA);
    float ph = __fmul_rn((float)exp((double)dhv), hsA);
    float hpw = __fmul_rn(0.5f, pw), hph = __fmul_rn(0.5f, ph);
    float x1 = __fsub_rn(pcx, hpw);
    float y1 = __fsub_rn(pcy, hph);
    float x2 = __fsub_rn(__fadd_rn(pcx, hpw), 1.0f);
    float y2 = __fsub_rn(__fadd_rn(pcy, hph), 1.0f);
    x1 = fminf(fmaxf(x1, 0.0f), wmax);
    y1 = fminf(fmaxf(y1, 0.0f), hmax);
    x2 = fminf(fmaxf(x2, 0.0f), wmax);
    y2 = fminf(fmaxf(y2, 0.0f), hmax);
    float ws2 = __fadd_rn(__fsub_rn(x2, x1), 1.0f);
    float hs2 = __fadd_rn(__fsub_rn(y2, y1), 1.0f);
    int v = (ws2 >= msz) && (hs2 >= msz) &&
            (__fadd_rn(x1, __fmul_rn(ws2, 0.5f)) < im_w) &&
            (__fadd_rn(y1, __fmul_rn(hs2, 0.5f)) < im_h);
    boxes[b * RSTRIDE + q] = make_float4(x1, y1, x2, y2);
    scores[b * RSTRIDE + q] = sc;
    valid[b * RSTRIDE + q] = v;
  }
}

__global__ __launch_bounds__(64) void nms_mask_kernel(const float4* __restrict__ boxes,
                                                      u64* __restrict__ mask) {
  int jb = blockIdx.x, ib = blockIdx.y, b = blockIdx.z;
  if (jb < ib) return;   // upper triangle only (j > i needed)
  int t = threadIdx.x;
  __shared__ float4 jbox[64];
  __shared__ float jarea[64];
  int jbase = jb * 64;
  int jcount = min(64, PRE - jbase);
  if (t < jcount) {
    float4 bj = boxes[b * RSTRIDE + jbase + t];
    jbox[t] = bj;
    jarea[t] = areaf(bj);
  }
  __syncthreads();
  int i = ib * 64 + t;
  if (i >= PRE) return;
  float4 bi = boxes[b * RSTRIDE + i];
  float ai = areaf(bi);
  u64 word = 0ULL;
  for (int jj = 0; jj < jcount; ++jj) {
    int j = jbase + jj;
    if (j <= i) continue;
    float4 bj = jbox[jj];
    float iw = fmaxf(__fadd_rn(__fsub_rn(fminf(bi.z, bj.z), fmaxf(bi.x, bj.x)), 1.0f), 0.0f);
    float ih = fmaxf(__fadd_rn(__fsub_rn(fminf(bi.w, bj.w), fmaxf(bi.y, bj.y)), 1.0f), 0.0f);
    float inter = __fmul_rn(iw, ih);
    float denom = __fsub_rn(__fadd_rn(ai, jarea[jj]), inter);
    float iou = inter / denom;
    if (iou > 0.7f) word |= (1ULL << jj);
  }
  mask[((size_t)(b * RSTRIDE) + i) * ROWW + jb] = word;
}

__global__ __launch_bounds__(64) void seq_nms_kernel(
    const u64* __restrict__ mask, const int* __restrict__ valid,
    const float4* __restrict__ boxes, const float* __restrict__ scores,
    float* __restrict__ out) {
  int b = blockIdx.x;
  int lane = threadIdx.x;
  __shared__ int keeplist[PRE];     // 8 KB
  __shared__ u64 rowbuf[64 * ROWW]; // 16 KB
  __shared__ int vbuf[64];
  __shared__ int kcnt_sh;
  u64 rem = 0ULL;                   // lanes 0..31 hold removed-bit words
  int K = 0;                        // tracked on lane 0
  for (int c0 = 0; c0 < PRE; c0 += 64) {
    const u64* src = mask + ((size_t)(b * RSTRIDE) + c0) * ROWW;
    for (int q = lane; q < 64 * ROWW; q += 64) rowbuf[q] = src[q];
    {
      int idx = c0 + lane;
      vbuf[lane] = (idx < PRE) ? valid[b * RSTRIDE + idx] : 0;
    }
    __syncthreads();
    int cend = min(64, PRE - c0);
    for (int ii = 0; ii < cend; ++ii) {
      int i = c0 + ii;
      int wsel = i >> 6;
      u64 wv = __shfl(rem, wsel, 64);
      bool keep = vbuf[ii] && !((wv >> (i & 63)) & 1ULL);
      if (keep) {
        if (lane == 0) { keeplist[K] = i; K++; }
        if (lane >= wsel && lane < ROWW) rem |= rowbuf[ii * ROWW + lane];
      }
    }
    __syncthreads();
  }
  if (lane == 0) kcnt_sh = K;
  __syncthreads();
  K = kcnt_sh;
  float* rois = out;
  float* probs = out + (size_t)BN * POST * 5;
  for (int r = lane; r < POST; r += 64) {
    float x1 = 0.f, y1 = 0.f, x2 = 0.f, y2 = 0.f, pr = 0.f;
    if (r < K) {
      int i = keeplist[r];
      float4 bb = boxes[b * RSTRIDE + i];
      x1 = bb.x; y1 = bb.y; x2 = bb.z; y2 = bb.w;
      pr = scores[b * RSTRIDE + i];
    }
    size_t ro = (size_t)(b * POST + r) * 5;
    rois[ro + 0] = (float)b;
    rois[ro + 1] = x1; rois[ro + 2] = y1; rois[ro + 3] = x2; rois[ro + 4] = y2;
    probs[b * POST + r] = pr;
  }
}

extern "C" void kernel_launch(void* const* d_in, const int* in_sizes, int n_in,
                              void* d_out, int out_size, void* d_ws, size_t ws_size,
                              hipStream_t stream) {
  const float* cls    = (const float*)d_in[0];
  const float* bbox   = (const float*)d_in[1];
  const float* iminfo = (const float*)d_in[2];
  const float* anch   = (const float*)d_in[3];
  char* ws = (char*)d_ws;
  u32* hist  = (u32*)(ws + OFF_HIST);
  u32* ccnt  = (u32*)(ws + OFF_CCNT);
  u32* thr   = (u32*)(ws + OFF_THR);
  u64* cand  = (u64*)(ws + OFF_CAND);
  float4* boxes = (float4*)(ws + OFF_BOX);
  float* scores = (float*)(ws + OFF_SCORE);
  int* valid    = (int*)(ws + OFF_VALID);
  u64* mask     = (u64*)(ws + OFF_MASK);
  float* out = (float*)d_out;

  // zero hist + candidate counters
  zero_kernel<<<2049, 256, 0, stream>>>((u32*)ws, 524352);
  hist_kernel<<<(NTOT + 255) / 256, 256, 0, stream>>>(cls, hist);
  thresh_kernel<<<BN, 1024, 0, stream>>>(hist, thr);
  gather_kernel<<<(NTOT + 255) / 256, 256, 0, stream>>>(cls, thr, ccnt, cand);
  sort_transform_kernel<<<BN, 1024, 0, stream>>>(cand, ccnt, bbox, iminfo, anch,
                                                 boxes, scores, valid);
  nms_mask_kernel<<<dim3(32, 32, BN), 64, 0, stream>>>(boxes, mask);
  seq_nms_kernel<<<BN, 64, 0, stream>>>(mask, valid, boxes, scores, out);
}

// Round 2
// 1123.724 us; speedup vs baseline: 1.0756x; 1.0756x over previous
//
#include <hip/hip_runtime.h>
#include <hip/hip_bf16.h>
#include <math.h>

#define BN 8
#define AN 15
#define HH 100
#define WW 168
#define HW (HH*WW)           // 16800
#define NPI (AN*HW)          // 252000 scores per image
#define NTOT (BN*NPI)        // 2016000
#define PRE 2000
#define POST 1000
#define CAP 8192             // candidate buffer per image (power of 2 for bitonic)
#define ROWW 32              // u64 words per NMS mask row (2000 bits -> 32 words)
#define NCHUNK 32            // ceil(PRE/64)
#define RSTRIDE 2048         // padded per-image row stride

typedef unsigned int u32;
typedef unsigned long long u64;

// ---- workspace layout (bytes) ----
#define OFF_HIST   0            // 8*65536*4 = 2097152
#define OFF_CCNT   2097152      // 8*4
#define OFF_THR    2097408      // 8*4
#define OFF_CAND   2098176      // 8*8192*8 = 524288
#define OFF_BOX    2622464      // 8*2048*16 = 262144
#define OFF_SCORE  2884608      // 8*2048*4
#define OFF_VALID  2950144      // 8*2048*4
#define OFF_MASK   3015680      // 8*2048*32*8 = 4194304  (total ~6.9 MB)

__device__ __forceinline__ u32 fmono(float s) {
  u32 u = __float_as_uint(s);
  return (u & 0x80000000u) ? ~u : (u | 0x80000000u);
}
__device__ __forceinline__ float funmono(u32 m) {
  u32 u = (m & 0x80000000u) ? (m ^ 0x80000000u) : ~m;
  return __uint_as_float(u);
}
__device__ __forceinline__ float areaf(float4 bx) {
  return __fmul_rn(__fadd_rn(__fsub_rn(bx.z, bx.x), 1.0f),
                   __fadd_rn(__fsub_rn(bx.w, bx.y), 1.0f));
}

__global__ void zero_kernel(u32* p, int n) {
  int i = blockIdx.x * blockDim.x + threadIdx.x;
  if (i < n) p[i] = 0u;
}

__global__ void hist_kernel(const float* __restrict__ cls, u32* __restrict__ hist) {
  int tid = blockIdx.x * blockDim.x + threadIdx.x;
  if (tid >= NTOT) return;
  int b = tid / NPI;
  u32 m = fmono(cls[tid]);
  atomicAdd(&hist[(b << 16) + (m >> 16)], 1u);
}

// parallel suffix-scan threshold finder (was lane-0 serial ~1100 dependent loads)
__global__ __launch_bounds__(1024) void thresh_kernel(const u32* __restrict__ hist,
                                                      u32* __restrict__ thr) {
  int b = blockIdx.x;
  int t = threadIdx.x;
  __shared__ u32 sfx[1024];
  const u32* hb = hist + (b << 16);
  u32 s = 0;
  for (int k = 0; k < 64; ++k) s += hb[t * 64 + k];
  sfx[t] = s;
  __syncthreads();
  // inclusive suffix scan: sfx[t] = sum_{u>=t} seg[u]
  for (int d = 1; d < 1024; d <<= 1) {
    u32 add = (t + d < 1024) ? sfx[t + d] : 0u;
    __syncthreads();
    sfx[t] += add;
    __syncthreads();
  }
  if (t == 0 && sfx[0] < (u32)PRE) thr[b] = 0u;
  if (sfx[t] >= (u32)PRE && (t == 1023 || sfx[t + 1] < (u32)PRE)) {
    u32 a2 = (t == 1023) ? 0u : sfx[t + 1];
    u32 T = (u32)(t * 64);
    for (int k = 63; k >= 0; --k) {
      a2 += hb[t * 64 + k];
      if (a2 >= (u32)PRE) { T = (u32)(t * 64 + k); break; }
    }
    thr[b] = T;
  }
}

__global__ void gather_kernel(const float* __restrict__ cls, const u32* __restrict__ thr,
                              u32* __restrict__ ccnt, u64* __restrict__ cand) {
  int tid = blockIdx.x * blockDim.x + threadIdx.x;
  if (tid >= NTOT) return;
  int b = tid / NPI;
  int r = tid - b * NPI;
  u32 m = fmono(cls[tid]);
  if ((m >> 16) >= thr[b]) {
    u32 pos = atomicAdd(&ccnt[b], 1u);
    if (pos < CAP) {
      int a  = r / HW;
      int hw = r - a * HW;
      u32 i  = (u32)(hw * AN + a);   // transposed flat index (h*W + w)*A + a
      cand[b * CAP + pos] = ((u64)m << 32) | (u32)(~i);
    }
  }
}

__global__ __launch_bounds__(1024) void sort_transform_kernel(
    const u64* __restrict__ cand, const u32* __restrict__ ccnt,
    const float* __restrict__ bbox, const float* __restrict__ iminfo,
    const float* __restrict__ anch,
    float4* __restrict__ boxes, float* __restrict__ scores, int* __restrict__ valid) {
  __shared__ u64 keys[CAP];   // 64 KB
  int b = blockIdx.x;
  int t = threadIdx.x;
  u32 cnt = ccnt[b];
  if (cnt > CAP) cnt = CAP;
  for (int q = t; q < CAP; q += 1024) keys[q] = (q < (int)cnt) ? cand[b * CAP + q] : 0ULL;
  __syncthreads();
  // bitonic sort, descending
  for (u32 k = 2; k <= CAP; k <<= 1) {
    for (u32 j = k >> 1; j > 0; j >>= 1) {
      for (int p = 0; p < CAP / 2 / 1024; ++p) {
        u32 idx = (u32)t + (u32)p * 1024u;           // 0..4095
        u32 base = ((idx & ~(j - 1)) << 1) | (idx & (j - 1));
        u32 partner = base + j;
        bool up = ((base & k) == 0);
        u64 A = keys[base], B = keys[partner];
        bool sw = up ? (A < B) : (A > B);
        if (sw) { keys[base] = B; keys[partner] = A; }
      }
      __syncthreads();
    }
  }
  // transform the top PRE
  float im_h = iminfo[b * 3 + 0], im_w = iminfo[b * 3 + 1], im_s = iminfo[b * 3 + 2];
  float wmax = __fsub_rn(im_w, 1.0f), hmax = __fsub_rn(im_h, 1.0f);
  float msz = __fmul_rn(0.0f, im_s);
  const float BCLIP = (float)4.135166556742356;  // log(1000/16)
  for (int q = t; q < PRE; q += 1024) {
    u64 key = keys[q];
    u32 i = ~((u32)key);
    float sc = funmono((u32)(key >> 32));
    int a = (int)(i % AN);
    int pp = (int)(i / AN);
    int w = pp % WW;
    int h = pp / WW;
    float sx = (float)(w * 8), sy = (float)(h * 8);
    float ax1 = __fadd_rn(anch[a * 4 + 0], sx);
    float ay1 = __fadd_rn(anch[a * 4 + 1], sy);
    float ax2 = __fadd_rn(anch[a * 4 + 2], sx);
    float ay2 = __fadd_rn(anch[a * 4 + 3], sy);
    float wsA = __fadd_rn(__fsub_rn(ax2, ax1), 1.0f);
    float hsA = __fadd_rn(__fsub_rn(ay2, ay1), 1.0f);
    float cx = __fadd_rn(ax1, __fmul_rn(0.5f, wsA));
    float cy = __fadd_rn(ay1, __fmul_rn(0.5f, hsA));
    const float* dp = bbox + ((size_t)b * (4 * AN) + 4 * a) * HW + (size_t)h * WW + w;
    float dx = dp[0], dy = dp[HW], dwv = dp[2 * HW], dhv = dp[3 * HW];
    dwv = fminf(dwv, BCLIP);
    dhv = fminf(dhv, BCLIP);
    float pcx = __fadd_rn(__fmul_rn(dx, wsA), cx);
    float pcy = __fadd_rn(__fmul_rn(dy, hsA), cy);
    float pw = __fmul_rn((float)exp((double)dwv), wsA);
    float ph = __fmul_rn((float)exp((double)dhv), hsA);
    float hpw = __fmul_rn(0.5f, pw), hph = __fmul_rn(0.5f, ph);
    float x1 = __fsub_rn(pcx, hpw);
    float y1 = __fsub_rn(pcy, hph);
    float x2 = __fsub_rn(__fadd_rn(pcx, hpw), 1.0f);
    float y2 = __fsub_rn(__fadd_rn(pcy, hph), 1.0f);
    x1 = fminf(fmaxf(x1, 0.0f), wmax);
    y1 = fminf(fmaxf(y1, 0.0f), hmax);
    x2 = fminf(fmaxf(x2, 0.0f), wmax);
    y2 = fminf(fmaxf(y2, 0.0f), hmax);
    float ws2 = __fadd_rn(__fsub_rn(x2, x1), 1.0f);
    float hs2 = __fadd_rn(__fsub_rn(y2, y1), 1.0f);
    int v = (ws2 >= msz) && (hs2 >= msz) &&
            (__fadd_rn(x1, __fmul_rn(ws2, 0.5f)) < im_w) &&
            (__fadd_rn(y1, __fmul_rn(hs2, 0.5f)) < im_h);
    boxes[b * RSTRIDE + q] = make_float4(x1, y1, x2, y2);
    scores[b * RSTRIDE + q] = sc;
    valid[b * RSTRIDE + q] = v;
  }
}

__global__ __launch_bounds__(64) void nms_mask_kernel(const float4* __restrict__ boxes,
                                                      u64* __restrict__ mask) {
  int jb = blockIdx.x, ib = blockIdx.y, b = blockIdx.z;
  if (jb < ib) return;   // upper triangle only (j > i needed)
  int t = threadIdx.x;
  __shared__ float4 jbox[64];
  __shared__ float jarea[64];
  int jbase = jb * 64;
  int jcount = min(64, PRE - jbase);
  if (t < jcount) {
    float4 bj = boxes[b * RSTRIDE + jbase + t];
    jbox[t] = bj;
    jarea[t] = areaf(bj);
  }
  __syncthreads();
  int i = ib * 64 + t;
  if (i >= PRE) return;
  float4 bi = boxes[b * RSTRIDE + i];
  float ai = areaf(bi);
  u64 word = 0ULL;
  for (int jj = 0; jj < jcount; ++jj) {
    int j = jbase + jj;
    if (j <= i) continue;
    float4 bj = jbox[jj];
    float iw = fmaxf(__fadd_rn(__fsub_rn(fminf(bi.z, bj.z), fmaxf(bi.x, bj.x)), 1.0f), 0.0f);
    float ih = fmaxf(__fadd_rn(__fsub_rn(fminf(bi.w, bj.w), fmaxf(bi.y, bj.y)), 1.0f), 0.0f);
    float inter = __fmul_rn(iw, ih);
    float denom = __fsub_rn(__fadd_rn(ai, jarea[jj]), inter);
    float iou = inter / denom;
    if (iou > 0.7f) word |= (1ULL << jj);
  }
  mask[((size_t)(b * RSTRIDE) + i) * ROWW + jb] = word;
}

// Serial greedy NMS scan. Critical path per iteration is now only
// bit-test(cur) -> cndmask -> or (no per-iteration shfl: the removed-word
// index i>>6 is constant within a 64-chunk, so `cur` is seeded by ONE shfl
// per chunk and updated via LDS-broadcast reads that don't depend on rem).
__global__ __launch_bounds__(64) void seq_nms_kernel(
    const u64* __restrict__ mask, const int* __restrict__ valid,
    const float4* __restrict__ boxes, const float* __restrict__ scores,
    float* __restrict__ out) {
  int b = blockIdx.x;
  int lane = threadIdx.x;
  __shared__ u64 rowbuf[64 * ROWW]; // 16 KB
  __shared__ u64 kbits[NCHUNK];
  __shared__ int chunkoff[NCHUNK + 1];
  __shared__ int keeplist[PRE];     // 8 KB
  u64 rem = 0ULL;                   // lane L (<32) holds removed-bits word L

  for (int c = 0; c < NCHUNK; ++c) {
    int c0 = c * 64;
    int cend = min(64, PRE - c0);
    const u64* src = mask + ((size_t)(b * RSTRIDE) + c0) * ROWW;
    for (int q = lane; q < cend * ROWW; q += 64) rowbuf[q] = src[q];
    int v = 0;
    if (lane < cend) v = valid[b * RSTRIDE + c0 + lane];
    u64 vb = __ballot(v != 0);           // uniform 64-bit valid mask for chunk
    u64 cur = __shfl(rem, c, 64);        // removed word c so far (uniform)
    __syncthreads();
    u64 keepb = 0ULL;
    for (int ii = 0; ii < cend; ++ii) {
      u64 w = rowbuf[ii * ROWW + c];     // broadcast read, prefetchable
      bool keep = ((vb >> ii) & 1ULL) && !((cur >> ii) & 1ULL);
      if (keep) {                         // wave-uniform branch
        cur |= w;
        keepb |= (1ULL << ii);
      }
    }
    // fold kept rows into distributed rem (off the serial critical path)
    if (lane < ROWW) {
      u64 kb = keepb;
      while (kb) {
        int ii = __ffsll((long long)kb) - 1;
        rem |= rowbuf[ii * ROWW + lane];
        kb &= kb - 1;
      }
    }
    if (lane == 0) kbits[c] = keepb;
    __syncthreads();                     // before rowbuf overwrite
  }

  // compact keep list: prefix of popcounts, then rank-scatter
  if (lane == 0) {
    int acc = 0;
    for (int c = 0; c < NCHUNK; ++c) { chunkoff[c] = acc; acc += __popcll(kbits[c]); }
    chunkoff[NCHUNK] = acc;
  }
  __syncthreads();
  for (int c = 0; c < NCHUNK; ++c) {
    u64 word = kbits[c];
    if ((word >> lane) & 1ULL) {
      int rank = (int)__popcll(word & ((1ULL << lane) - 1ULL));
      keeplist[chunkoff[c] + rank] = c * 64 + lane;
    }
  }
  __syncthreads();
  int K = chunkoff[NCHUNK];

  float* rois = out;
  float* probs = out + (size_t)BN * POST * 5;
  for (int r = lane; r < POST; r += 64) {
    float x1 = 0.f, y1 = 0.f, x2 = 0.f, y2 = 0.f, pr = 0.f;
    if (r < K) {
      int i = keeplist[r];
      float4 bb = boxes[b * RSTRIDE + i];
      x1 = bb.x; y1 = bb.y; x2 = bb.z; y2 = bb.w;
      pr = scores[b * RSTRIDE + i];
    }
    size_t ro = (size_t)(b * POST + r) * 5;
    rois[ro + 0] = (float)b;
    rois[ro + 1] = x1; rois[ro + 2] = y1; rois[ro + 3] = x2; rois[ro + 4] = y2;
    probs[b * POST + r] = pr;
  }
}

extern "C" void kernel_launch(void* const* d_in, const int* in_sizes, int n_in,
                              void* d_out, int out_size, void* d_ws, size_t ws_size,
                              hipStream_t stream) {
  const float* cls    = (const float*)d_in[0];
  const float* bbox   = (const float*)d_in[1];
  const float* iminfo = (const float*)d_in[2];
  const float* anch   = (const float*)d_in[3];
  char* ws = (char*)d_ws;
  u32* hist  = (u32*)(ws + OFF_HIST);
  u32* ccnt  = (u32*)(ws + OFF_CCNT);
  u32* thr   = (u32*)(ws + OFF_THR);
  u64* cand  = (u64*)(ws + OFF_CAND);
  float4* boxes = (float4*)(ws + OFF_BOX);
  float* scores = (float*)(ws + OFF_SCORE);
  int* valid    = (int*)(ws + OFF_VALID);
  u64* mask     = (u64*)(ws + OFF_MASK);
  float* out = (float*)d_out;

  zero_kernel<<<2049, 256, 0, stream>>>((u32*)ws, 524352);
  hist_kernel<<<(NTOT + 255) / 256, 256, 0, stream>>>(cls, hist);
  thresh_kernel<<<BN, 1024, 0, stream>>>(hist, thr);
  gather_kernel<<<(NTOT + 255) / 256, 256, 0, stream>>>(cls, thr, ccnt, cand);
  sort_transform_kernel<<<BN, 1024, 0, stream>>>(cand, ccnt, bbox, iminfo, anch,
                                                 boxes, scores, valid);
  nms_mask_kernel<<<dim3(32, 32, BN), 64, 0, stream>>>(boxes, mask);
  seq_nms_kernel<<<BN, 64, 0, stream>>>(mask, valid, boxes, scores, out);
}

// Round 4
// 644.065 us; speedup vs baseline: 1.8766x; 1.7447x over previous
//
#include <hip/hip_runtime.h>
#include <hip/hip_bf16.h>
#include <math.h>

#define BN 8
#define AN 15
#define HH 100
#define WW 168
#define HW (HH*WW)           // 16800
#define NPI (AN*HW)          // 252000 scores per image
#define NTOT (BN*NPI)        // 2016000
#define PRE 2000
#define POST 1000
#define CAP 4096             // candidate buffer per image (threshold-bucket bound ~3000)
#define ROWW 32              // u64 words per NMS mask row (2000 bits -> 32 words)
#define NCHUNK 32            // ceil(PRE/64)
#define RSTRIDE 2048         // padded per-image row stride

typedef unsigned int u32;
typedef unsigned long long u64;

// ---- workspace layout (bytes) ----
// NOTE R3 bug: thr was a 128-byte region but indexed thr[b*32] (128 B/image)
// -> b>=1 aliased cand -> races -> garbage thresholds -> pad-key decode ->
// OOB bbox read -> GPU fault. thr now has its own 1024-byte region.
#define OFF_HIST   0            // 8*65536*4 = 2097152
#define OFF_CCNT   2097152      // 8*128 = 1024
#define OFF_THR    2098176      // 8*128 = 1024
#define OFF_CAND   2099200      // 8*4096*8 = 262144
#define OFF_BOX    2361344      // 8*2048*16 = 262144
#define OFF_SCORE  2623488      // 8*2048*4 = 65536
#define OFF_VALID  2689024      // 8*2048*4 = 65536
#define OFF_MASK   2754560      // 8*2048*32*8 = 4194304  (total ~6.6 MB)

__device__ __forceinline__ u32 fmono(float s) {
  u32 u = __float_as_uint(s);
  return (u & 0x80000000u) ? ~u : (u | 0x80000000u);
}
__device__ __forceinline__ float funmono(u32 m) {
  u32 u = (m & 0x80000000u) ? (m ^ 0x80000000u) : ~m;
  return __uint_as_float(u);
}
__device__ __forceinline__ float areaf(float4 bx) {
  return __fmul_rn(__fadd_rn(__fsub_rn(bx.z, bx.x), 1.0f),
                   __fadd_rn(__fsub_rn(bx.w, bx.y), 1.0f));
}

__global__ void zero_kernel(u32* p, int n) {
  int i = blockIdx.x * blockDim.x + threadIdx.x;
  if (i < n) p[i] = 0u;
}

__global__ void hist_kernel(const float* __restrict__ cls, u32* __restrict__ hist) {
  int tid = blockIdx.x * blockDim.x + threadIdx.x;
  if (tid >= NTOT) return;
  int b = tid / NPI;
  u32 m = fmono(cls[tid]);
  atomicAdd(&hist[(b << 16) + (m >> 16)], 1u);
}

// parallel suffix-scan threshold finder
__global__ __launch_bounds__(1024) void thresh_kernel(const u32* __restrict__ hist,
                                                      u32* __restrict__ thr) {
  int b = blockIdx.x;
  int t = threadIdx.x;
  __shared__ u32 sfx[1024];
  const u32* hb = hist + (b << 16);
  u32 s = 0;
  for (int k = 0; k < 64; ++k) s += hb[t * 64 + k];
  sfx[t] = s;
  __syncthreads();
  for (int d = 1; d < 1024; d <<= 1) {
    u32 add = (t + d < 1024) ? sfx[t + d] : 0u;
    __syncthreads();
    sfx[t] += add;
    __syncthreads();
  }
  if (t == 0 && sfx[0] < (u32)PRE) thr[b * 32] = 0u;
  if (sfx[t] >= (u32)PRE && (t == 1023 || sfx[t + 1] < (u32)PRE)) {
    u32 a2 = (t == 1023) ? 0u : sfx[t + 1];
    u32 T = (u32)(t * 64);
    for (int k = 63; k >= 0; --k) {
      a2 += hb[t * 64 + k];
      if (a2 >= (u32)PRE) { T = (u32)(t * 64 + k); break; }
    }
    thr[b * 32] = T;
  }
}

// wave-aggregated gather: one atomic per wave with >=1 candidate
__global__ void gather_kernel(const float* __restrict__ cls, const u32* __restrict__ thr,
                              u32* __restrict__ ccnt, u64* __restrict__ cand) {
  int tid = blockIdx.x * blockDim.x + threadIdx.x;   // grid exactly covers NTOT
  int b = tid / NPI;
  int r = tid - b * NPI;
  u32 m = fmono(cls[tid]);
  bool pass = (m >> 16) >= thr[b * 32];
  int lane = threadIdx.x & 63;
  int b0 = __shfl(b, 0, 64);
  bool uni = (__ballot(b != b0) == 0ULL);
  u32 pos = 0xffffffffu;
  if (uni) {
    u64 bal = __ballot(pass);
    if (bal) {
      int leader = __ffsll((long long)bal) - 1;
      u32 base = 0;
      if (lane == leader) base = atomicAdd(&ccnt[b * 32], (u32)__popcll(bal));
      base = __shfl(base, leader, 64);
      if (pass) pos = base + (u32)__popcll(bal & ((1ULL << lane) - 1ULL));
    }
  } else if (pass) {
    pos = atomicAdd(&ccnt[b * 32], 1u);
  }
  if (pass && pos < CAP) {
    int a  = r / HW;
    int hw = r - a * HW;
    u32 i  = (u32)(hw * AN + a);   // transposed flat index (h*W + w)*A + a
    cand[(size_t)b * CAP + pos] = ((u64)m << 32) | (u32)(~i);
  }
}

__global__ __launch_bounds__(1024) void sort_transform_kernel(
    const u64* __restrict__ cand, const u32* __restrict__ ccnt,
    const float* __restrict__ bbox, const float* __restrict__ iminfo,
    const float* __restrict__ anch,
    float4* __restrict__ boxes, float* __restrict__ scores, int* __restrict__ valid) {
  __shared__ u64 keys[CAP];   // 32 KB
  int b = blockIdx.x;
  int t = threadIdx.x;
  u32 cnt = ccnt[b * 32];
  if (cnt > CAP) cnt = CAP;
  for (int q = t; q < CAP; q += 1024) keys[q] = (q < (int)cnt) ? cand[(size_t)b * CAP + q] : 0ULL;
  __syncthreads();
  // bitonic sort, descending
  for (u32 k = 2; k <= CAP; k <<= 1) {
    for (u32 j = k >> 1; j > 0; j >>= 1) {
      for (int p = 0; p < CAP / 2 / 1024; ++p) {
        u32 idx = (u32)t + (u32)p * 1024u;           // 0..CAP/2-1
        u32 base = ((idx & ~(j - 1)) << 1) | (idx & (j - 1));
        u32 partner = base + j;
        bool up = ((base & k) == 0);
        u64 A = keys[base], B = keys[partner];
        bool sw = up ? (A < B) : (A > B);
        if (sw) { keys[base] = B; keys[partner] = A; }
      }
      __syncthreads();
    }
  }
  // transform the top PRE
  float im_h = iminfo[b * 3 + 0], im_w = iminfo[b * 3 + 1], im_s = iminfo[b * 3 + 2];
  float wmax = __fsub_rn(im_w, 1.0f), hmax = __fsub_rn(im_h, 1.0f);
  float msz = __fmul_rn(0.0f, im_s);
  const float BCLIP = (float)4.135166556742356;  // log(1000/16)
  for (int q = t; q < PRE; q += 1024) {
    u64 key = keys[q];
    u32 i = ~((u32)key);
    // defensive: pad keys (q >= cnt) decode to i >= NPI -> never dereference
    if (q >= (int)cnt || i >= (u32)NPI) {
      boxes[b * RSTRIDE + q] = make_float4(0.f, 0.f, 0.f, 0.f);
      scores[b * RSTRIDE + q] = 0.f;
      valid[b * RSTRIDE + q] = 0;
      continue;
    }
    float sc = funmono((u32)(key >> 32));
    int a = (int)(i % AN);
    int pp = (int)(i / AN);
    int w = pp % WW;
    int h = pp / WW;
    float sx = (float)(w * 8), sy = (float)(h * 8);
    float ax1 = __fadd_rn(anch[a * 4 + 0], sx);
    float ay1 = __fadd_rn(anch[a * 4 + 1], sy);
    float ax2 = __fadd_rn(anch[a * 4 + 2], sx);
    float ay2 = __fadd_rn(anch[a * 4 + 3], sy);
    float wsA = __fadd_rn(__fsub_rn(ax2, ax1), 1.0f);
    float hsA = __fadd_rn(__fsub_rn(ay2, ay1), 1.0f);
    float cx = __fadd_rn(ax1, __fmul_rn(0.5f, wsA));
    float cy = __fadd_rn(ay1, __fmul_rn(0.5f, hsA));
    const float* dp = bbox + ((size_t)b * (4 * AN) + 4 * a) * HW + (size_t)h * WW + w;
    float dx = dp[0], dy = dp[HW], dwv = dp[2 * HW], dhv = dp[3 * HW];
    dwv = fminf(dwv, BCLIP);
    dhv = fminf(dhv, BCLIP);
    float pcx = __fadd_rn(__fmul_rn(dx, wsA), cx);
    float pcy = __fadd_rn(__fmul_rn(dy, hsA), cy);
    float pw = __fmul_rn((float)exp((double)dwv), wsA);
    float ph = __fmul_rn((float)exp((double)dhv), hsA);
    float hpw = __fmul_rn(0.5f, pw), hph = __fmul_rn(0.5f, ph);
    float x1 = __fsub_rn(pcx, hpw);
    float y1 = __fsub_rn(pcy, hph);
    float x2 = __fsub_rn(__fadd_rn(pcx, hpw), 1.0f);
    float y2 = __fsub_rn(__fadd_rn(pcy, hph), 1.0f);
    x1 = fminf(fmaxf(x1, 0.0f), wmax);
    y1 = fminf(fmaxf(y1, 0.0f), hmax);
    x2 = fminf(fmaxf(x2, 0.0f), wmax);
    y2 = fminf(fmaxf(y2, 0.0f), hmax);
    float ws2 = __fadd_rn(__fsub_rn(x2, x1), 1.0f);
    float hs2 = __fadd_rn(__fsub_rn(y2, y1), 1.0f);
    int v = (ws2 >= msz) && (hs2 >= msz) &&
            (__fadd_rn(x1, __fmul_rn(ws2, 0.5f)) < im_w) &&
            (__fadd_rn(y1, __fmul_rn(hs2, 0.5f)) < im_h);
    boxes[b * RSTRIDE + q] = make_float4(x1, y1, x2, y2);
    scores[b * RSTRIDE + q] = sc;
    valid[b * RSTRIDE + q] = v;
  }
}

__global__ __launch_bounds__(64) void nms_mask_kernel(const float4* __restrict__ boxes,
                                                      u64* __restrict__ mask) {
  int jb = blockIdx.x, ib = blockIdx.y, b = blockIdx.z;
  if (jb < ib) return;   // upper triangle only (j > i needed)
  int t = threadIdx.x;
  __shared__ float4 jbox[64];
  __shared__ float jarea[64];
  int jbase = jb * 64;
  int jcount = min(64, PRE - jbase);
  if (t < jcount) {
    float4 bj = boxes[b * RSTRIDE + jbase + t];
    jbox[t] = bj;
    jarea[t] = areaf(bj);
  }
  __syncthreads();
  int i = ib * 64 + t;
  if (i >= PRE) return;
  float4 bi = boxes[b * RSTRIDE + i];
  float ai = areaf(bi);
  u64 word = 0ULL;
  for (int jj = 0; jj < jcount; ++jj) {
    int j = jbase + jj;
    if (j <= i) continue;
    float4 bj = jbox[jj];
    float iw = fmaxf(__fadd_rn(__fsub_rn(fminf(bi.z, bj.z), fmaxf(bi.x, bj.x)), 1.0f), 0.0f);
    float ih = fmaxf(__fadd_rn(__fsub_rn(fminf(bi.w, bj.w), fmaxf(bi.y, bj.y)), 1.0f), 0.0f);
    float inter = __fmul_rn(iw, ih);
    float denom = __fsub_rn(__fadd_rn(ai, jarea[jj]), inter);
    float iou = inter / denom;
    if (iou > 0.7f) word |= (1ULL << jj);
  }
  mask[((size_t)(b * RSTRIDE) + i) * ROWW + jb] = word;
}

// Serial greedy NMS, single wave per image, register double-buffered staging.
__global__ __launch_bounds__(64) void seq_nms_kernel(
    const u64* __restrict__ mask, const int* __restrict__ valid,
    const float4* __restrict__ boxes, const float* __restrict__ scores,
    float* __restrict__ out) {
  int b = blockIdx.x;
  int lane = threadIdx.x;
  __shared__ u64 rowbuf[2][64 * ROWW];   // 2 x 16 KB
  __shared__ u64 kbits_s[NCHUNK];
  __shared__ int chunkoff[NCHUNK];
  __shared__ int keeplist[PRE];
  __shared__ int Ksh;

  const u64* base = mask + (size_t)b * RSTRIDE * ROWW;
  {
    const uint4* s4 = (const uint4*)base;
    uint4* d4 = (uint4*)rowbuf[0];
#pragma unroll
    for (int k = 0; k < 16; ++k) d4[k * 64 + lane] = s4[k * 64 + lane];
  }
  __syncthreads();

  u64 rem = 0ULL;      // lane L (<32) holds removed-bits word L
  u64 cur = 0ULL;      // removed word for current chunk (uniform, replicated)
  int lw = lane & 31;
  for (int c = 0; c < NCHUNK; ++c) {
    int c0 = c * 64;
    int cend = min(64, PRE - c0);
    uint4 pf[16];
    if (c + 1 < NCHUNK) {
      const uint4* s4 = (const uint4*)(base + (size_t)(c0 + 64) * ROWW);
#pragma unroll
      for (int k = 0; k < 16; ++k) pf[k] = s4[k * 64 + lane];
    }
    int v = 0;
    if (lane < cend) v = valid[b * RSTRIDE + c0 + lane];
    u64 vb = __ballot(v != 0);           // uniform valid mask for chunk
    const u64* rb = rowbuf[c & 1];
    u64 keepb = 0ULL, foldw = 0ULL;
#pragma unroll
    for (int ii = 0; ii < 64; ++ii) {
      u64 wl = rb[ii * ROWW + lw];       // per-lane word (fold source)
      u64 wc = rb[ii * ROWW + c];        // broadcast word c (scan source)
      u64 km = (((vb >> ii) & 1ULL) & ((~(cur >> ii)) & 1ULL)) ? ~0ULL : 0ULL;
      cur   |= wc & km;                  // the only serial chain
      foldw |= wl & km;
      keepb |= (1ULL << ii) & km;
    }
    rem |= foldw;
    if (lane == 0) kbits_s[c] = keepb;
    cur = __shfl(rem, c + 1, 64);        // seed next chunk's removed word
    __syncthreads();
    if (c + 1 < NCHUNK) {
      uint4* d4 = (uint4*)rowbuf[(c + 1) & 1];
#pragma unroll
      for (int k = 0; k < 16; ++k) d4[k * 64 + lane] = pf[k];
    }
    __syncthreads();
  }

  // compact keep list: wave prefix-scan of per-chunk popcounts
  {
    int pc = (lane < NCHUNK) ? (int)__popcll(kbits_s[lane]) : 0;
    int inc = pc;
    for (int d = 1; d < 64; d <<= 1) {
      int n = __shfl_up(inc, d, 64);
      if (lane >= d) inc += n;
    }
    if (lane < NCHUNK) chunkoff[lane] = inc - pc;   // exclusive
    if (lane == NCHUNK - 1) Ksh = inc;
  }
  __syncthreads();
  for (int c = 0; c < NCHUNK; ++c) {
    u64 word = kbits_s[c];
    if ((word >> lane) & 1ULL) {
      int rank = (int)__popcll(word & ((1ULL << lane) - 1ULL));
      keeplist[chunkoff[c] + rank] = c * 64 + lane;
    }
  }
  __syncthreads();
  int K = Ksh;

  float* rois = out;
  float* probs = out + (size_t)BN * POST * 5;
  for (int r = lane; r < POST; r += 64) {
    float x1 = 0.f, y1 = 0.f, x2 = 0.f, y2 = 0.f, pr = 0.f;
    if (r < K) {
      int i = keeplist[r];
      float4 bb = boxes[b * RSTRIDE + i];
      x1 = bb.x; y1 = bb.y; x2 = bb.z; y2 = bb.w;
      pr = scores[b * RSTRIDE + i];
    }
    size_t ro = (size_t)(b * POST + r) * 5;
    rois[ro + 0] = (float)b;
    rois[ro + 1] = x1; rois[ro + 2] = y1; rois[ro + 3] = x2; rois[ro + 4] = y2;
    probs[b * POST + r] = pr;
  }
}

extern "C" void kernel_launch(void* const* d_in, const int* in_sizes, int n_in,
                              void* d_out, int out_size, void* d_ws, size_t ws_size,
                              hipStream_t stream) {
  const float* cls    = (const float*)d_in[0];
  const float* bbox   = (const float*)d_in[1];
  const float* iminfo = (const float*)d_in[2];
  const float* anch   = (const float*)d_in[3];
  char* ws = (char*)d_ws;
  u32* hist  = (u32*)(ws + OFF_HIST);
  u32* ccnt  = (u32*)(ws + OFF_CCNT);
  u32* thr   = (u32*)(ws + OFF_THR);
  u64* cand  = (u64*)(ws + OFF_CAND);
  float4* boxes = (float4*)(ws + OFF_BOX);
  float* scores = (float*)(ws + OFF_SCORE);
  int* valid    = (int*)(ws + OFF_VALID);
  u64* mask     = (u64*)(ws + OFF_MASK);
  float* out = (float*)d_out;

  zero_kernel<<<2050, 256, 0, stream>>>((u32*)ws, (2097152 + 1024) / 4);
  hist_kernel<<<(NTOT + 255) / 256, 256, 0, stream>>>(cls, hist);
  thresh_kernel<<<BN, 1024, 0, stream>>>(hist, thr);
  gather_kernel<<<NTOT / 256, 256, 0, stream>>>(cls, thr, ccnt, cand);
  sort_transform_kernel<<<BN, 1024, 0, stream>>>(cand, ccnt, bbox, iminfo, anch,
                                                 boxes, scores, valid);
  nms_mask_kernel<<<dim3(32, 32, BN), 64, 0, stream>>>(boxes, mask);
  seq_nms_kernel<<<BN, 64, 0, stream>>>(mask, valid, boxes, scores, out);
}

// Round 5
// 395.388 us; speedup vs baseline: 3.0569x; 1.6289x over previous
//
#include <hip/hip_runtime.h>
#include <hip/hip_bf16.h>
#include <math.h>

#define BN 8
#define AN 15
#define HH 100
#define WW 168
#define HW (HH*WW)           // 16800
#define NPI (AN*HW)          // 252000 scores per image
#define NTOT (BN*NPI)        // 2016000
#define PRE 2000
#define POST 1000
#define CAP 4096             // candidate buffer per image (threshold-bucket bound ~3000)
#define ROWW 32              // u64 words per NMS mask row (2000 bits -> 32 words)
#define NCHUNK 32            // ceil(PRE/64)
#define RSTRIDE 2048         // padded per-image row stride
#define EPB 4096             // elements per hist block
#define HBLK 62              // ceil(NPI/EPB)

typedef unsigned int u32;
typedef unsigned long long u64;

// ---- workspace layout (bytes) ----
#define OFF_H1     0            // 8*256*4 = 8192
#define OFF_H2     8192         // 8192
#define OFF_CSTAR  16384        // 8*128 = 1024 (cstar[b*32], base[b*32+1])
#define OFF_CCNT   17408        // 1024
#define OFF_THR    18432        // 1024
#define OFF_CAND   19456        // 8*4096*8 = 262144
#define OFF_BOX    281600       // 8*2048*16 = 262144
#define OFF_SCORE  543744       // 65536
#define OFF_VALID  609280       // 65536
#define OFF_MASK   674816       // 8*2048*32*8 = 4194304 (total ~4.9 MB)
#define ZERO_WORDS ((OFF_CAND) / 4)

__device__ __forceinline__ u32 fmono(float s) {
  u32 u = __float_as_uint(s);
  return (u & 0x80000000u) ? ~u : (u | 0x80000000u);
}
__device__ __forceinline__ float funmono(u32 m) {
  u32 u = (m & 0x80000000u) ? (m ^ 0x80000000u) : ~m;
  return __uint_as_float(u);
}
__device__ __forceinline__ float areaf(float4 bx) {
  return __fmul_rn(__fadd_rn(__fsub_rn(bx.z, bx.x), 1.0f),
                   __fadd_rn(__fsub_rn(bx.w, bx.y), 1.0f));
}

__global__ void zero_kernel(u32* p, int n) {
  int i = blockIdx.x * blockDim.x + threadIdx.x;
  if (i < n) p[i] = 0u;
}

// phase-1 histogram: 256 coarse buckets (m>>24), LDS-privatized 4-way
__global__ __launch_bounds__(256) void hist1_kernel(const float* __restrict__ cls,
                                                    u32* __restrict__ h1) {
  __shared__ u32 lh[1024];   // 4 copies x 256 buckets
  int b = blockIdx.y;
  int t = threadIdx.x;
  for (int q = t; q < 1024; q += 256) lh[q] = 0u;
  __syncthreads();
  int start = blockIdx.x * EPB;
  int end = min(start + EPB, NPI);
  const float* p = cls + (size_t)b * NPI;
  u32 copy = ((u32)t & 3u) << 8;
  for (int i = start + t; i < end; i += 256) {
    u32 m = fmono(p[i]);
    atomicAdd(&lh[copy | (m >> 24)], 1u);
  }
  __syncthreads();
  u32 s = lh[t] + lh[t + 256] + lh[t + 512] + lh[t + 768];
  if (s) atomicAdd(&h1[(b << 8) + t], s);
}

// pick coarse bucket c*: suffix scan of 256 coarse counts
__global__ __launch_bounds__(256) void coarse_kernel(const u32* __restrict__ h1,
                                                     u32* __restrict__ cstar) {
  int b = blockIdx.x;
  int t = threadIdx.x;
  __shared__ u32 sfx[256];
  sfx[t] = h1[(b << 8) + t];
  __syncthreads();
  for (int d = 1; d < 256; d <<= 1) {
    u32 add = (t + d < 256) ? sfx[t + d] : 0u;
    __syncthreads();
    sfx[t] += add;
    __syncthreads();
  }
  if (t == 0 && sfx[0] < (u32)PRE) { cstar[b * 32] = 0u; cstar[b * 32 + 1] = sfx[1]; }
  if (sfx[t] >= (u32)PRE && (t == 255 || sfx[t + 1] < (u32)PRE)) {
    cstar[b * 32] = (u32)t;
    cstar[b * 32 + 1] = (t == 255) ? 0u : sfx[t + 1];   // count strictly above c*
  }
}

// phase-2 histogram: 256 fine buckets ((m>>16)&0xFF), filtered to m>>24==c*
__global__ __launch_bounds__(256) void hist2_kernel(const float* __restrict__ cls,
                                                    const u32* __restrict__ cstar,
                                                    u32* __restrict__ h2) {
  __shared__ u32 lh[256];
  int b = blockIdx.y;
  int t = threadIdx.x;
  lh[t] = 0u;
  __syncthreads();
  u32 cs = cstar[b * 32];
  int start = blockIdx.x * EPB;
  int end = min(start + EPB, NPI);
  const float* p = cls + (size_t)b * NPI;
  for (int i = start + t; i < end; i += 256) {
    u32 m = fmono(p[i]);
    if ((m >> 24) == cs) atomicAdd(&lh[(m >> 16) & 0xFFu], 1u);
  }
  __syncthreads();
  if (lh[t]) atomicAdd(&h2[(b << 8) + t], lh[t]);
}

// final 16-bit threshold: thr16 = (c*<<8) | k*, largest k with base+sfx[k] >= PRE
__global__ __launch_bounds__(256) void fine_kernel(const u32* __restrict__ h2,
                                                   const u32* __restrict__ cstar,
                                                   u32* __restrict__ thr) {
  int b = blockIdx.x;
  int t = threadIdx.x;
  __shared__ u32 sfx[256];
  sfx[t] = h2[(b << 8) + t];
  __syncthreads();
  for (int d = 1; d < 256; d <<= 1) {
    u32 add = (t + d < 256) ? sfx[t + d] : 0u;
    __syncthreads();
    sfx[t] += add;
    __syncthreads();
  }
  u32 cs = cstar[b * 32], base = cstar[b * 32 + 1];
  if (t == 0 && base + sfx[0] < (u32)PRE) thr[b * 32] = (cs << 8);
  if (base + sfx[t] >= (u32)PRE && (t == 255 || base + sfx[t + 1] < (u32)PRE))
    thr[b * 32] = (cs << 8) | (u32)t;
}

// wave-aggregated gather: one atomic per wave with >=1 candidate
__global__ void gather_kernel(const float* __restrict__ cls, const u32* __restrict__ thr,
                              u32* __restrict__ ccnt, u64* __restrict__ cand) {
  int tid = blockIdx.x * blockDim.x + threadIdx.x;   // grid exactly covers NTOT
  int b = tid / NPI;
  int r = tid - b * NPI;
  u32 m = fmono(cls[tid]);
  bool pass = (m >> 16) >= thr[b * 32];
  int lane = threadIdx.x & 63;
  int b0 = __shfl(b, 0, 64);
  bool uni = (__ballot(b != b0) == 0ULL);
  u32 pos = 0xffffffffu;
  if (uni) {
    u64 bal = __ballot(pass);
    if (bal) {
      int leader = __ffsll((long long)bal) - 1;
      u32 base = 0;
      if (lane == leader) base = atomicAdd(&ccnt[b * 32], (u32)__popcll(bal));
      base = __shfl(base, leader, 64);
      if (pass) pos = base + (u32)__popcll(bal & ((1ULL << lane) - 1ULL));
    }
  } else if (pass) {
    pos = atomicAdd(&ccnt[b * 32], 1u);
  }
  if (pass && pos < CAP) {
    int a  = r / HW;
    int hw = r - a * HW;
    u32 i  = (u32)(hw * AN + a);   // transposed flat index (h*W + w)*A + a
    cand[(size_t)b * CAP + pos] = ((u64)m << 32) | (u32)(~i);
  }
}

__global__ __launch_bounds__(1024) void sort_transform_kernel(
    const u64* __restrict__ cand, const u32* __restrict__ ccnt,
    const float* __restrict__ bbox, const float* __restrict__ iminfo,
    const float* __restrict__ anch,
    float4* __restrict__ boxes, float* __restrict__ scores, int* __restrict__ valid) {
  __shared__ u64 keys[CAP];   // 32 KB
  int b = blockIdx.x;
  int t = threadIdx.x;
  u32 cnt = ccnt[b * 32];
  if (cnt > CAP) cnt = CAP;
  for (int q = t; q < CAP; q += 1024) keys[q] = (q < (int)cnt) ? cand[(size_t)b * CAP + q] : 0ULL;
  __syncthreads();
  // bitonic sort, descending
  for (u32 k = 2; k <= CAP; k <<= 1) {
    for (u32 j = k >> 1; j > 0; j >>= 1) {
      for (int p = 0; p < CAP / 2 / 1024; ++p) {
        u32 idx = (u32)t + (u32)p * 1024u;           // 0..CAP/2-1
        u32 base = ((idx & ~(j - 1)) << 1) | (idx & (j - 1));
        u32 partner = base + j;
        bool up = ((base & k) == 0);
        u64 A = keys[base], B = keys[partner];
        bool sw = up ? (A < B) : (A > B);
        if (sw) { keys[base] = B; keys[partner] = A; }
      }
      __syncthreads();
    }
  }
  // transform the top PRE
  float im_h = iminfo[b * 3 + 0], im_w = iminfo[b * 3 + 1], im_s = iminfo[b * 3 + 2];
  float wmax = __fsub_rn(im_w, 1.0f), hmax = __fsub_rn(im_h, 1.0f);
  float msz = __fmul_rn(0.0f, im_s);
  const float BCLIP = (float)4.135166556742356;  // log(1000/16)
  for (int q = t; q < PRE; q += 1024) {
    u64 key = keys[q];
    u32 i = ~((u32)key);
    // defensive: pad keys (q >= cnt) decode to i >= NPI -> never dereference
    if (q >= (int)cnt || i >= (u32)NPI) {
      boxes[b * RSTRIDE + q] = make_float4(0.f, 0.f, 0.f, 0.f);
      scores[b * RSTRIDE + q] = 0.f;
      valid[b * RSTRIDE + q] = 0;
      continue;
    }
    float sc = funmono((u32)(key >> 32));
    int a = (int)(i % AN);
    int pp = (int)(i / AN);
    int w = pp % WW;
    int h = pp / WW;
    float sx = (float)(w * 8), sy = (float)(h * 8);
    float ax1 = __fadd_rn(anch[a * 4 + 0], sx);
    float ay1 = __fadd_rn(anch[a * 4 + 1], sy);
    float ax2 = __fadd_rn(anch[a * 4 + 2], sx);
    float ay2 = __fadd_rn(anch[a * 4 + 3], sy);
    float wsA = __fadd_rn(__fsub_rn(ax2, ax1), 1.0f);
    float hsA = __fadd_rn(__fsub_rn(ay2, ay1), 1.0f);
    float cx = __fadd_rn(ax1, __fmul_rn(0.5f, wsA));
    float cy = __fadd_rn(ay1, __fmul_rn(0.5f, hsA));
    const float* dp = bbox + ((size_t)b * (4 * AN) + 4 * a) * HW + (size_t)h * WW + w;
    float dx = dp[0], dy = dp[HW], dwv = dp[2 * HW], dhv = dp[3 * HW];
    dwv = fminf(dwv, BCLIP);
    dhv = fminf(dhv, BCLIP);
    float pcx = __fadd_rn(__fmul_rn(dx, wsA), cx);
    float pcy = __fadd_rn(__fmul_rn(dy, hsA), cy);
    float pw = __fmul_rn((float)exp((double)dwv), wsA);
    float ph = __fmul_rn((float)exp((double)dhv), hsA);
    float hpw = __fmul_rn(0.5f, pw), hph = __fmul_rn(0.5f, ph);
    float x1 = __fsub_rn(pcx, hpw);
    float y1 = __fsub_rn(pcy, hph);
    float x2 = __fsub_rn(__fadd_rn(pcx, hpw), 1.0f);
    float y2 = __fsub_rn(__fadd_rn(pcy, hph), 1.0f);
    x1 = fminf(fmaxf(x1, 0.0f), wmax);
    y1 = fminf(fmaxf(y1, 0.0f), hmax);
    x2 = fminf(fmaxf(x2, 0.0f), wmax);
    y2 = fminf(fmaxf(y2, 0.0f), hmax);
    float ws2 = __fadd_rn(__fsub_rn(x2, x1), 1.0f);
    float hs2 = __fadd_rn(__fsub_rn(y2, y1), 1.0f);
    int v = (ws2 >= msz) && (hs2 >= msz) &&
            (__fadd_rn(x1, __fmul_rn(ws2, 0.5f)) < im_w) &&
            (__fadd_rn(y1, __fmul_rn(hs2, 0.5f)) < im_h);
    boxes[b * RSTRIDE + q] = make_float4(x1, y1, x2, y2);
    scores[b * RSTRIDE + q] = sc;
    valid[b * RSTRIDE + q] = v;
  }
}

__global__ __launch_bounds__(64) void nms_mask_kernel(const float4* __restrict__ boxes,
                                                      u64* __restrict__ mask) {
  int jb = blockIdx.x, ib = blockIdx.y, b = blockIdx.z;
  if (jb < ib) return;   // upper triangle only (j > i needed)
  int t = threadIdx.x;
  __shared__ float4 jbox[64];
  __shared__ float jarea[64];
  int jbase = jb * 64;
  int jcount = min(64, PRE - jbase);
  if (t < jcount) {
    float4 bj = boxes[b * RSTRIDE + jbase + t];
    jbox[t] = bj;
    jarea[t] = areaf(bj);
  }
  __syncthreads();
  int i = ib * 64 + t;
  if (i >= PRE) return;
  float4 bi = boxes[b * RSTRIDE + i];
  float ai = areaf(bi);
  u64 word = 0ULL;
  for (int jj = 0; jj < jcount; ++jj) {
    int j = jbase + jj;
    if (j <= i) continue;
    float4 bj = jbox[jj];
    float iw = fmaxf(__fadd_rn(__fsub_rn(fminf(bi.z, bj.z), fmaxf(bi.x, bj.x)), 1.0f), 0.0f);
    float ih = fmaxf(__fadd_rn(__fsub_rn(fminf(bi.w, bj.w), fmaxf(bi.y, bj.y)), 1.0f), 0.0f);
    float inter = __fmul_rn(iw, ih);
    float denom = __fsub_rn(__fadd_rn(ai, jarea[jj]), inter);
    float iou = inter / denom;
    if (iou > 0.7f) word |= (1ULL << jj);
  }
  mask[((size_t)(b * RSTRIDE) + i) * ROWW + jb] = word;
}

// Serial greedy NMS, single wave per image, register double-buffered staging.
__global__ __launch_bounds__(64) void seq_nms_kernel(
    const u64* __restrict__ mask, const int* __restrict__ valid,
    const float4* __restrict__ boxes, const float* __restrict__ scores,
    float* __restrict__ out) {
  int b = blockIdx.x;
  int lane = threadIdx.x;
  __shared__ u64 rowbuf[2][64 * ROWW];   // 2 x 16 KB
  __shared__ u64 kbits_s[NCHUNK];
  __shared__ int chunkoff[NCHUNK];
  __shared__ int keeplist[PRE];
  __shared__ int Ksh;

  const u64* base = mask + (size_t)b * RSTRIDE * ROWW;
  {
    const uint4* s4 = (const uint4*)base;
    uint4* d4 = (uint4*)rowbuf[0];
#pragma unroll
    for (int k = 0; k < 16; ++k) d4[k * 64 + lane] = s4[k * 64 + lane];
  }
  __syncthreads();

  u64 rem = 0ULL;      // lane L (<32) holds removed-bits word L
  u64 cur = 0ULL;      // removed word for current chunk (uniform, replicated)
  int lw = lane & 31;
  for (int c = 0; c < NCHUNK; ++c) {
    int c0 = c * 64;
    int cend = min(64, PRE - c0);
    uint4 pf[16];
    if (c + 1 < NCHUNK) {
      const uint4* s4 = (const uint4*)(base + (size_t)(c0 + 64) * ROWW);
#pragma unroll
      for (int k = 0; k < 16; ++k) pf[k] = s4[k * 64 + lane];
    }
    int v = 0;
    if (lane < cend) v = valid[b * RSTRIDE + c0 + lane];
    u64 vb = __ballot(v != 0);           // uniform valid mask for chunk
    const u64* rb = rowbuf[c & 1];
    u64 keepb = 0ULL, foldw = 0ULL;
#pragma unroll
    for (int ii = 0; ii < 64; ++ii) {
      u64 wl = rb[ii * ROWW + lw];       // per-lane word (fold source)
      u64 wc = rb[ii * ROWW + c];        // broadcast word c (scan source)
      u64 km = (((vb >> ii) & 1ULL) & ((~(cur >> ii)) & 1ULL)) ? ~0ULL : 0ULL;
      cur   |= wc & km;                  // the only serial chain
      foldw |= wl & km;
      keepb |= (1ULL << ii) & km;
    }
    rem |= foldw;
    if (lane == 0) kbits_s[c] = keepb;
    cur = __shfl(rem, c + 1, 64);        // seed next chunk's removed word
    __syncthreads();
    if (c + 1 < NCHUNK) {
      uint4* d4 = (uint4*)rowbuf[(c + 1) & 1];
#pragma unroll
      for (int k = 0; k < 16; ++k) d4[k * 64 + lane] = pf[k];
    }
    __syncthreads();
  }

  // compact keep list: wave prefix-scan of per-chunk popcounts
  {
    int pc = (lane < NCHUNK) ? (int)__popcll(kbits_s[lane]) : 0;
    int inc = pc;
    for (int d = 1; d < 64; d <<= 1) {
      int n = __shfl_up(inc, d, 64);
      if (lane >= d) inc += n;
    }
    if (lane < NCHUNK) chunkoff[lane] = inc - pc;   // exclusive
    if (lane == NCHUNK - 1) Ksh = inc;
  }
  __syncthreads();
  for (int c = 0; c < NCHUNK; ++c) {
    u64 word = kbits_s[c];
    if ((word >> lane) & 1ULL) {
      int rank = (int)__popcll(word & ((1ULL << lane) - 1ULL));
      keeplist[chunkoff[c] + rank] = c * 64 + lane;
    }
  }
  __syncthreads();
  int K = Ksh;

  float* rois = out;
  float* probs = out + (size_t)BN * POST * 5;
  for (int r = lane; r < POST; r += 64) {
    float x1 = 0.f, y1 = 0.f, x2 = 0.f, y2 = 0.f, pr = 0.f;
    if (r < K) {
      int i = keeplist[r];
      float4 bb = boxes[b * RSTRIDE + i];
      x1 = bb.x; y1 = bb.y; x2 = bb.z; y2 = bb.w;
      pr = scores[b * RSTRIDE + i];
    }
    size_t ro = (size_t)(b * POST + r) * 5;
    rois[ro + 0] = (float)b;
    rois[ro + 1] = x1; rois[ro + 2] = y1; rois[ro + 3] = x2; rois[ro + 4] = y2;
    probs[b * POST + r] = pr;
  }
}

extern "C" void kernel_launch(void* const* d_in, const int* in_sizes, int n_in,
                              void* d_out, int out_size, void* d_ws, size_t ws_size,
                              hipStream_t stream) {
  const float* cls    = (const float*)d_in[0];
  const float* bbox   = (const float*)d_in[1];
  const float* iminfo = (const float*)d_in[2];
  const float* anch   = (const float*)d_in[3];
  char* ws = (char*)d_ws;
  u32* h1    = (u32*)(ws + OFF_H1);
  u32* h2    = (u32*)(ws + OFF_H2);
  u32* cstar = (u32*)(ws + OFF_CSTAR);
  u32* ccnt  = (u32*)(ws + OFF_CCNT);
  u32* thr   = (u32*)(ws + OFF_THR);
  u64* cand  = (u64*)(ws + OFF_CAND);
  float4* boxes = (float4*)(ws + OFF_BOX);
  float* scores = (float*)(ws + OFF_SCORE);
  int* valid    = (int*)(ws + OFF_VALID);
  u64* mask     = (u64*)(ws + OFF_MASK);
  float* out = (float*)d_out;

  zero_kernel<<<(ZERO_WORDS + 255) / 256, 256, 0, stream>>>((u32*)ws, ZERO_WORDS);
  hist1_kernel<<<dim3(HBLK, BN), 256, 0, stream>>>(cls, h1);
  coarse_kernel<<<BN, 256, 0, stream>>>(h1, cstar);
  hist2_kernel<<<dim3(HBLK, BN), 256, 0, stream>>>(cls, cstar, h2);
  fine_kernel<<<BN, 256, 0, stream>>>(h2, cstar, thr);
  gather_kernel<<<NTOT / 256, 256, 0, stream>>>(cls, thr, ccnt, cand);
  sort_transform_kernel<<<BN, 1024, 0, stream>>>(cand, ccnt, bbox, iminfo, anch,
                                                 boxes, scores, valid);
  nms_mask_kernel<<<dim3(32, 32, BN), 64, 0, stream>>>(boxes, mask);
  seq_nms_kernel<<<BN, 64, 0, stream>>>(mask, valid, boxes, scores, out);
}

// Round 6
// 359.190 us; speedup vs baseline: 3.3650x; 1.1008x over previous
//
#include <hip/hip_runtime.h>
#include <hip/hip_bf16.h>
#include <math.h>

#define BN 8
#define AN 15
#define HH 100
#define WW 168
#define HW (HH*WW)           // 16800
#define NPI (AN*HW)          // 252000 scores per image
#define NTOT (BN*NPI)        // 2016000
#define PRE 2000
#define POST 1000
#define CAP 4096             // candidate buffer per image (threshold-bucket bound ~3000)
#define ROWW 32              // u64 words per NMS mask row (2000 bits -> 32 words)
#define NCHUNK 32            // ceil(PRE/64)
#define RSTRIDE 2048         // padded per-image row stride
#define EPB 4096             // elements per hist block
#define HBLK 62              // ceil(NPI/EPB)

typedef unsigned int u32;
typedef unsigned long long u64;

// ---- workspace layout (bytes) ----
#define OFF_H1     0            // 8*256*4 = 8192
#define OFF_H2     8192         // 8192
#define OFF_CSTAR  16384        // 8*128 = 1024 (cstar[b*32], base[b*32+1])
#define OFF_CCNT   17408        // 1024
#define OFF_THR    18432        // 1024
#define OFF_CAND   19456        // 8*4096*8 = 262144
#define OFF_BOX    281600       // 8*2048*16 = 262144
#define OFF_SCORE  543744       // 65536
#define OFF_VALID  609280       // 65536
#define OFF_MASK   674816       // 8*2048*32*8 = 4194304 (total ~4.9 MB)
#define ZERO_WORDS ((OFF_CAND) / 4)

__device__ __forceinline__ u32 fmono(float s) {
  u32 u = __float_as_uint(s);
  return (u & 0x80000000u) ? ~u : (u | 0x80000000u);
}
__device__ __forceinline__ float funmono(u32 m) {
  u32 u = (m & 0x80000000u) ? (m ^ 0x80000000u) : ~m;
  return __uint_as_float(u);
}
__device__ __forceinline__ float areaf(float4 bx) {
  return __fmul_rn(__fadd_rn(__fsub_rn(bx.z, bx.x), 1.0f),
                   __fadd_rn(__fsub_rn(bx.w, bx.y), 1.0f));
}

__global__ void zero_kernel(u32* p, int n) {
  int i = blockIdx.x * blockDim.x + threadIdx.x;
  if (i < n) p[i] = 0u;
}

// phase-1 histogram: 256 coarse buckets (m>>24), LDS-privatized 4-way
__global__ __launch_bounds__(256) void hist1_kernel(const float* __restrict__ cls,
                                                    u32* __restrict__ h1) {
  __shared__ u32 lh[1024];   // 4 copies x 256 buckets
  int b = blockIdx.y;
  int t = threadIdx.x;
  for (int q = t; q < 1024; q += 256) lh[q] = 0u;
  __syncthreads();
  int start = blockIdx.x * EPB;
  int end = min(start + EPB, NPI);
  const float* p = cls + (size_t)b * NPI;
  u32 copy = ((u32)t & 3u) << 8;
  for (int i = start + t; i < end; i += 256) {
    u32 m = fmono(p[i]);
    atomicAdd(&lh[copy | (m >> 24)], 1u);
  }
  __syncthreads();
  u32 s = lh[t] + lh[t + 256] + lh[t + 512] + lh[t + 768];
  if (s) atomicAdd(&h1[(b << 8) + t], s);
}

// pick coarse bucket c*: suffix scan of 256 coarse counts
__global__ __launch_bounds__(256) void coarse_kernel(const u32* __restrict__ h1,
                                                     u32* __restrict__ cstar) {
  int b = blockIdx.x;
  int t = threadIdx.x;
  __shared__ u32 sfx[256];
  sfx[t] = h1[(b << 8) + t];
  __syncthreads();
  for (int d = 1; d < 256; d <<= 1) {
    u32 add = (t + d < 256) ? sfx[t + d] : 0u;
    __syncthreads();
    sfx[t] += add;
    __syncthreads();
  }
  if (t == 0 && sfx[0] < (u32)PRE) { cstar[b * 32] = 0u; cstar[b * 32 + 1] = sfx[1]; }
  if (sfx[t] >= (u32)PRE && (t == 255 || sfx[t + 1] < (u32)PRE)) {
    cstar[b * 32] = (u32)t;
    cstar[b * 32 + 1] = (t == 255) ? 0u : sfx[t + 1];   // count strictly above c*
  }
}

// phase-2 histogram: 256 fine buckets ((m>>16)&0xFF), filtered to m>>24==c*
__global__ __launch_bounds__(256) void hist2_kernel(const float* __restrict__ cls,
                                                    const u32* __restrict__ cstar,
                                                    u32* __restrict__ h2) {
  __shared__ u32 lh[256];
  int b = blockIdx.y;
  int t = threadIdx.x;
  lh[t] = 0u;
  __syncthreads();
  u32 cs = cstar[b * 32];
  int start = blockIdx.x * EPB;
  int end = min(start + EPB, NPI);
  const float* p = cls + (size_t)b * NPI;
  for (int i = start + t; i < end; i += 256) {
    u32 m = fmono(p[i]);
    if ((m >> 24) == cs) atomicAdd(&lh[(m >> 16) & 0xFFu], 1u);
  }
  __syncthreads();
  if (lh[t]) atomicAdd(&h2[(b << 8) + t], lh[t]);
}

// final 16-bit threshold: thr16 = (c*<<8) | k*, largest k with base+sfx[k] >= PRE
__global__ __launch_bounds__(256) void fine_kernel(const u32* __restrict__ h2,
                                                   const u32* __restrict__ cstar,
                                                   u32* __restrict__ thr) {
  int b = blockIdx.x;
  int t = threadIdx.x;
  __shared__ u32 sfx[256];
  sfx[t] = h2[(b << 8) + t];
  __syncthreads();
  for (int d = 1; d < 256; d <<= 1) {
    u32 add = (t + d < 256) ? sfx[t + d] : 0u;
    __syncthreads();
    sfx[t] += add;
    __syncthreads();
  }
  u32 cs = cstar[b * 32], base = cstar[b * 32 + 1];
  if (t == 0 && base + sfx[0] < (u32)PRE) thr[b * 32] = (cs << 8);
  if (base + sfx[t] >= (u32)PRE && (t == 255 || base + sfx[t + 1] < (u32)PRE))
    thr[b * 32] = (cs << 8) | (u32)t;
}

// wave-aggregated gather: one atomic per wave with >=1 candidate
__global__ void gather_kernel(const float* __restrict__ cls, const u32* __restrict__ thr,
                              u32* __restrict__ ccnt, u64* __restrict__ cand) {
  int tid = blockIdx.x * blockDim.x + threadIdx.x;   // grid exactly covers NTOT
  int b = tid / NPI;
  int r = tid - b * NPI;
  u32 m = fmono(cls[tid]);
  bool pass = (m >> 16) >= thr[b * 32];
  int lane = threadIdx.x & 63;
  int b0 = __shfl(b, 0, 64);
  bool uni = (__ballot(b != b0) == 0ULL);
  u32 pos = 0xffffffffu;
  if (uni) {
    u64 bal = __ballot(pass);
    if (bal) {
      int leader = __ffsll((long long)bal) - 1;
      u32 base = 0;
      if (lane == leader) base = atomicAdd(&ccnt[b * 32], (u32)__popcll(bal));
      base = __shfl(base, leader, 64);
      if (pass) pos = base + (u32)__popcll(bal & ((1ULL << lane) - 1ULL));
    }
  } else if (pass) {
    pos = atomicAdd(&ccnt[b * 32], 1u);
  }
  if (pass && pos < CAP) {
    int a  = r / HW;
    int hw = r - a * HW;
    u32 i  = (u32)(hw * AN + a);   // transposed flat index (h*W + w)*A + a
    cand[(size_t)b * CAP + pos] = ((u64)m << 32) | (u32)(~i);
  }
}

__global__ __launch_bounds__(1024) void sort_transform_kernel(
    const u64* __restrict__ cand, const u32* __restrict__ ccnt,
    const float* __restrict__ bbox, const float* __restrict__ iminfo,
    const float* __restrict__ anch,
    float4* __restrict__ boxes, float* __restrict__ scores, int* __restrict__ valid) {
  __shared__ u64 keys[CAP];   // 32 KB
  int b = blockIdx.x;
  int t = threadIdx.x;
  u32 cnt = ccnt[b * 32];
  if (cnt > CAP) cnt = CAP;
  for (int q = t; q < CAP; q += 1024) keys[q] = (q < (int)cnt) ? cand[(size_t)b * CAP + q] : 0ULL;
  __syncthreads();
  // bitonic sort, descending
  for (u32 k = 2; k <= CAP; k <<= 1) {
    for (u32 j = k >> 1; j > 0; j >>= 1) {
      for (int p = 0; p < CAP / 2 / 1024; ++p) {
        u32 idx = (u32)t + (u32)p * 1024u;           // 0..CAP/2-1
        u32 base = ((idx & ~(j - 1)) << 1) | (idx & (j - 1));
        u32 partner = base + j;
        bool up = ((base & k) == 0);
        u64 A = keys[base], B = keys[partner];
        bool sw = up ? (A < B) : (A > B);
        if (sw) { keys[base] = B; keys[partner] = A; }
      }
      __syncthreads();
    }
  }
  // transform the top PRE
  float im_h = iminfo[b * 3 + 0], im_w = iminfo[b * 3 + 1], im_s = iminfo[b * 3 + 2];
  float wmax = __fsub_rn(im_w, 1.0f), hmax = __fsub_rn(im_h, 1.0f);
  float msz = __fmul_rn(0.0f, im_s);
  const float BCLIP = (float)4.135166556742356;  // log(1000/16)
  for (int q = t; q < PRE; q += 1024) {
    u64 key = keys[q];
    u32 i = ~((u32)key);
    // defensive: pad keys (q >= cnt) decode to i >= NPI -> never dereference
    if (q >= (int)cnt || i >= (u32)NPI) {
      boxes[b * RSTRIDE + q] = make_float4(0.f, 0.f, 0.f, 0.f);
      scores[b * RSTRIDE + q] = 0.f;
      valid[b * RSTRIDE + q] = 0;
      continue;
    }
    float sc = funmono((u32)(key >> 32));
    int a = (int)(i % AN);
    int pp = (int)(i / AN);
    int w = pp % WW;
    int h = pp / WW;
    float sx = (float)(w * 8), sy = (float)(h * 8);
    float ax1 = __fadd_rn(anch[a * 4 + 0], sx);
    float ay1 = __fadd_rn(anch[a * 4 + 1], sy);
    float ax2 = __fadd_rn(anch[a * 4 + 2], sx);
    float ay2 = __fadd_rn(anch[a * 4 + 3], sy);
    float wsA = __fadd_rn(__fsub_rn(ax2, ax1), 1.0f);
    float hsA = __fadd_rn(__fsub_rn(ay2, ay1), 1.0f);
    float cx = __fadd_rn(ax1, __fmul_rn(0.5f, wsA));
    float cy = __fadd_rn(ay1, __fmul_rn(0.5f, hsA));
    const float* dp = bbox + ((size_t)b * (4 * AN) + 4 * a) * HW + (size_t)h * WW + w;
    float dx = dp[0], dy = dp[HW], dwv = dp[2 * HW], dhv = dp[3 * HW];
    dwv = fminf(dwv, BCLIP);
    dhv = fminf(dhv, BCLIP);
    float pcx = __fadd_rn(__fmul_rn(dx, wsA), cx);
    float pcy = __fadd_rn(__fmul_rn(dy, hsA), cy);
    float pw = __fmul_rn((float)exp((double)dwv), wsA);
    float ph = __fmul_rn((float)exp((double)dhv), hsA);
    float hpw = __fmul_rn(0.5f, pw), hph = __fmul_rn(0.5f, ph);
    float x1 = __fsub_rn(pcx, hpw);
    float y1 = __fsub_rn(pcy, hph);
    float x2 = __fsub_rn(__fadd_rn(pcx, hpw), 1.0f);
    float y2 = __fsub_rn(__fadd_rn(pcy, hph), 1.0f);
    x1 = fminf(fmaxf(x1, 0.0f), wmax);
    y1 = fminf(fmaxf(y1, 0.0f), hmax);
    x2 = fminf(fmaxf(x2, 0.0f), wmax);
    y2 = fminf(fmaxf(y2, 0.0f), hmax);
    float ws2 = __fadd_rn(__fsub_rn(x2, x1), 1.0f);
    float hs2 = __fadd_rn(__fsub_rn(y2, y1), 1.0f);
    int v = (ws2 >= msz) && (hs2 >= msz) &&
            (__fadd_rn(x1, __fmul_rn(ws2, 0.5f)) < im_w) &&
            (__fadd_rn(y1, __fmul_rn(hs2, 0.5f)) < im_h);
    boxes[b * RSTRIDE + q] = make_float4(x1, y1, x2, y2);
    scores[b * RSTRIDE + q] = sc;
    valid[b * RSTRIDE + q] = v;
  }
}

__global__ __launch_bounds__(64) void nms_mask_kernel(const float4* __restrict__ boxes,
                                                      u64* __restrict__ mask) {
  int jb = blockIdx.x, ib = blockIdx.y, b = blockIdx.z;
  if (jb < ib) return;   // upper triangle only (j > i needed)
  int t = threadIdx.x;
  __shared__ float4 jbox[64];
  __shared__ float jarea[64];
  int jbase = jb * 64;
  int jcount = min(64, PRE - jbase);
  if (t < jcount) {
    float4 bj = boxes[b * RSTRIDE + jbase + t];
    jbox[t] = bj;
    jarea[t] = areaf(bj);
  }
  __syncthreads();
  int i = ib * 64 + t;
  if (i >= PRE) return;
  float4 bi = boxes[b * RSTRIDE + i];
  float ai = areaf(bi);
  u64 word = 0ULL;
  for (int jj = 0; jj < jcount; ++jj) {
    int j = jbase + jj;
    if (j <= i) continue;
    float4 bj = jbox[jj];
    float iw = fmaxf(__fadd_rn(__fsub_rn(fminf(bi.z, bj.z), fmaxf(bi.x, bj.x)), 1.0f), 0.0f);
    float ih = fmaxf(__fadd_rn(__fsub_rn(fminf(bi.w, bj.w), fmaxf(bi.y, bj.y)), 1.0f), 0.0f);
    float inter = __fmul_rn(iw, ih);
    float denom = __fsub_rn(__fadd_rn(ai, jarea[jj]), inter);
    float iou = inter / denom;
    if (iou > 0.7f) word |= (1ULL << jj);
  }
  mask[((size_t)(b * RSTRIDE) + i) * ROWW + jb] = word;
}

// ---------------- seq NMS v3: register-resident tile, shfl diag broadcast ----
// Lane L holds word (L&31) of rows 2k+(L>>5) for k=0..31 (entire 16KB chunk
// in the wave's registers). Diagonal words reach all lanes via __shfl (128
// independent bpermutes the compiler hoists above the serial chain). Upper-
// triangular mask => bit ii of cur freezes after step ii => gate only on
// curbit, and keepb = vb & ~cur_final. Fold is register-only VALU.
__device__ __forceinline__ void nms_chunk(
    int c, const u64* __restrict__ base, u64 (&Rt)[32], u64 (&Pt)[32],
    const u64* __restrict__ vbufLDS, u64& rem, u64& cur,
    u64* __restrict__ kbits_s, int lane, int lw, int hf) {
  // prefetch next chunk's tile (independent of everything below)
  if (c + 1 < NCHUNK) {
    const u64* src = base + (size_t)((c + 1) * 64) * ROWW;
#pragma unroll
    for (int k = 0; k < 32; ++k) Pt[k] = src[(2 * k + hf) * ROWW + lw];
  }
  u64 vb = vbufLDS[c];
  int slo = c, shi = c + 32;   // source lanes holding diag words (even/odd rows)
#pragma unroll
  for (int s = 0; s < 4; ++s) {
    u64 e[16];
#pragma unroll
    for (int j = 0; j < 16; ++j) {
      int ii = s * 16 + j;
      u64 d = (u64)__shfl((long long)Rt[ii >> 1], (ii & 1) ? shi : slo, 64);
      u64 vbm = ((vb >> ii) & 1ULL) ? ~0ULL : 0ULL;
      e[j] = d & vbm;
    }
#pragma unroll
    for (int j = 0; j < 16; ++j) {
      int ii = s * 16 + j;
      cur |= ((cur >> ii) & 1ULL) ? 0ULL : e[j];   // the only serial chain
    }
  }
  u64 keepb = vb & ~cur;
  // fold kept rows into distributed rem (register-only)
#pragma unroll
  for (int k = 0; k < 32; ++k) {
    u64 km = ((keepb >> (2 * k + hf)) & 1ULL) ? ~0ULL : 0ULL;
    rem |= Rt[k] & km;
  }
  if (lane == 0) kbits_s[c] = keepb;
  // seed next chunk's removed word: word c+1 = even-half | odd-half
  int nw = (c + 1) & 31;
  u64 r0 = (u64)__shfl((long long)rem, nw, 64);
  u64 r1 = (u64)__shfl((long long)rem, nw + 32, 64);
  cur = r0 | r1;
}

__global__ __launch_bounds__(64) void seq_nms_kernel(
    const u64* __restrict__ mask, const int* __restrict__ valid,
    const float4* __restrict__ boxes, const float* __restrict__ scores,
    float* __restrict__ out) {
  int b = blockIdx.x;
  int lane = threadIdx.x;
  int lw = lane & 31, hf = lane >> 5;
  __shared__ u64 vbufLDS[NCHUNK];
  __shared__ u64 kbits_s[NCHUNK];
  __shared__ int chunkoff[NCHUNK];
  __shared__ int keeplist[PRE];
  __shared__ int Ksh;

  // preload valid bits: 32 independent loads, then ballots
  {
    int v[NCHUNK];
#pragma unroll
    for (int c = 0; c < NCHUNK; ++c) {
      int q = c * 64 + lane;
      v[c] = (q < PRE) ? valid[b * RSTRIDE + q] : 0;
    }
#pragma unroll
    for (int c = 0; c < NCHUNK; ++c) {
      u64 bl = __ballot(v[c] != 0);
      if (lane == 0) vbufLDS[c] = bl;
    }
  }
  __syncthreads();

  const u64* base = mask + (size_t)b * RSTRIDE * ROWW;
  u64 A[32], Bt[32];
  // load chunk 0 tile
#pragma unroll
  for (int k = 0; k < 32; ++k) A[k] = base[(2 * k + hf) * ROWW + lw];

  u64 rem = 0ULL, cur = 0ULL;
  for (int cc = 0; cc < NCHUNK; cc += 2) {
    nms_chunk(cc,     base, A,  Bt, vbufLDS, rem, cur, kbits_s, lane, lw, hf);
    nms_chunk(cc + 1, base, Bt, A,  vbufLDS, rem, cur, kbits_s, lane, lw, hf);
  }
  __syncthreads();

  // compact keep list: wave prefix-scan of per-chunk popcounts
  {
    int pc = (lane < NCHUNK) ? (int)__popcll(kbits_s[lane]) : 0;
    int inc = pc;
    for (int d = 1; d < 64; d <<= 1) {
      int n = __shfl_up(inc, d, 64);
      if (lane >= d) inc += n;
    }
    if (lane < NCHUNK) chunkoff[lane] = inc - pc;   // exclusive
    if (lane == NCHUNK - 1) Ksh = inc;
  }
  __syncthreads();
  for (int c = 0; c < NCHUNK; ++c) {
    u64 word = kbits_s[c];
    if ((word >> lane) & 1ULL) {
      int rank = (int)__popcll(word & ((1ULL << lane) - 1ULL));
      keeplist[chunkoff[c] + rank] = c * 64 + lane;
    }
  }
  __syncthreads();
  int K = Ksh;

  float* rois = out;
  float* probs = out + (size_t)BN * POST * 5;
  for (int r = lane; r < POST; r += 64) {
    float x1 = 0.f, y1 = 0.f, x2 = 0.f, y2 = 0.f, pr = 0.f;
    if (r < K) {
      int i = keeplist[r];
      float4 bb = boxes[b * RSTRIDE + i];
      x1 = bb.x; y1 = bb.y; x2 = bb.z; y2 = bb.w;
      pr = scores[b * RSTRIDE + i];
    }
    size_t ro = (size_t)(b * POST + r) * 5;
    rois[ro + 0] = (float)b;
    rois[ro + 1] = x1; rois[ro + 2] = y1; rois[ro + 3] = x2; rois[ro + 4] = y2;
    probs[b * POST + r] = pr;
  }
}

extern "C" void kernel_launch(void* const* d_in, const int* in_sizes, int n_in,
                              void* d_out, int out_size, void* d_ws, size_t ws_size,
                              hipStream_t stream) {
  const float* cls    = (const float*)d_in[0];
  const float* bbox   = (const float*)d_in[1];
  const float* iminfo = (const float*)d_in[2];
  const float* anch   = (const float*)d_in[3];
  char* ws = (char*)d_ws;
  u32* h1    = (u32*)(ws + OFF_H1);
  u32* h2    = (u32*)(ws + OFF_H2);
  u32* cstar = (u32*)(ws + OFF_CSTAR);
  u32* ccnt  = (u32*)(ws + OFF_CCNT);
  u32* thr   = (u32*)(ws + OFF_THR);
  u64* cand  = (u64*)(ws + OFF_CAND);
  float4* boxes = (float4*)(ws + OFF_BOX);
  float* scores = (float*)(ws + OFF_SCORE);
  int* valid    = (int*)(ws + OFF_VALID);
  u64* mask     = (u64*)(ws + OFF_MASK);
  float* out = (float*)d_out;

  zero_kernel<<<(ZERO_WORDS + 255) / 256, 256, 0, stream>>>((u32*)ws, ZERO_WORDS);
  hist1_kernel<<<dim3(HBLK, BN), 256, 0, stream>>>(cls, h1);
  coarse_kernel<<<BN, 256, 0, stream>>>(h1, cstar);
  hist2_kernel<<<dim3(HBLK, BN), 256, 0, stream>>>(cls, cstar, h2);
  fine_kernel<<<BN, 256, 0, stream>>>(h2, cstar, thr);
  gather_kernel<<<NTOT / 256, 256, 0, stream>>>(cls, thr, ccnt, cand);
  sort_transform_kernel<<<BN, 1024, 0, stream>>>(cand, ccnt, bbox, iminfo, anch,
                                                 boxes, scores, valid);
  nms_mask_kernel<<<dim3(32, 32, BN), 64, 0, stream>>>(boxes, mask);
  seq_nms_kernel<<<BN, 64, 0, stream>>>(mask, valid, boxes, scores, out);
}

// Round 7
// 351.530 us; speedup vs baseline: 3.4383x; 1.0218x over previous
//
#include <hip/hip_runtime.h>
#include <hip/hip_bf16.h>
#include <math.h>

#define BN 8
#define AN 15
#define HH 100
#define WW 168
#define HW (HH*WW)           // 16800
#define NPI (AN*HW)          // 252000 scores per image
#define NTOT (BN*NPI)        // 2016000
#define PRE 2000
#define POST 1000
#define CAP 4096             // candidate buffer per image (threshold-bucket bound ~3000)
#define ROWW 32              // u64 words per NMS mask row (2000 bits -> 32 words)
#define NCHUNK 32            // ceil(PRE/64)
#define RSTRIDE 2048         // padded per-image row stride
#define EPB 4096             // elements per hist block
#define HBLK 62              // ceil(NPI/EPB)

typedef unsigned int u32;
typedef unsigned long long u64;

// ---- workspace layout (bytes) ----
#define OFF_H1     0            // 8*256*4 = 8192
#define OFF_H2     8192         // 8192
#define OFF_CSTAR  16384        // 8*128 = 1024 (cstar[b*32], base[b*32+1])
#define OFF_CCNT   17408        // 1024
#define OFF_THR    18432        // 1024
#define OFF_CAND   19456        // 8*4096*8 = 262144
#define OFF_BOX    281600       // 8*2048*16 = 262144
#define OFF_SCORE  543744       // 65536
#define OFF_VALID  609280       // 65536
#define OFF_MASK   674816       // 8*2048*32*8 = 4194304 (total ~4.9 MB)
#define ZERO_WORDS ((OFF_CAND) / 4)   // only hist/counters need zeroing

__device__ __forceinline__ u32 fmono(float s) {
  u32 u = __float_as_uint(s);
  return (u & 0x80000000u) ? ~u : (u | 0x80000000u);
}
__device__ __forceinline__ float funmono(u32 m) {
  u32 u = (m & 0x80000000u) ? (m ^ 0x80000000u) : ~m;
  return __uint_as_float(u);
}
__device__ __forceinline__ float areaf(float4 bx) {
  return __fmul_rn(__fadd_rn(__fsub_rn(bx.z, bx.x), 1.0f),
                   __fadd_rn(__fsub_rn(bx.w, bx.y), 1.0f));
}

__global__ void zero_kernel(u32* p, int n) {
  int i = blockIdx.x * blockDim.x + threadIdx.x;
  if (i < n) p[i] = 0u;
}

// phase-1 histogram: 256 coarse buckets (m>>24), LDS-privatized 4-way
__global__ __launch_bounds__(256) void hist1_kernel(const float* __restrict__ cls,
                                                    u32* __restrict__ h1) {
  __shared__ u32 lh[1024];   // 4 copies x 256 buckets
  int b = blockIdx.y;
  int t = threadIdx.x;
  for (int q = t; q < 1024; q += 256) lh[q] = 0u;
  __syncthreads();
  int start = blockIdx.x * EPB;
  int end = min(start + EPB, NPI);
  const float* p = cls + (size_t)b * NPI;
  u32 copy = ((u32)t & 3u) << 8;
  for (int i = start + t; i < end; i += 256) {
    u32 m = fmono(p[i]);
    atomicAdd(&lh[copy | (m >> 24)], 1u);
  }
  __syncthreads();
  u32 s = lh[t] + lh[t + 256] + lh[t + 512] + lh[t + 768];
  if (s) atomicAdd(&h1[(b << 8) + t], s);
}

// pick coarse bucket c*: suffix scan of 256 coarse counts
__global__ __launch_bounds__(256) void coarse_kernel(const u32* __restrict__ h1,
                                                     u32* __restrict__ cstar) {
  int b = blockIdx.x;
  int t = threadIdx.x;
  __shared__ u32 sfx[256];
  sfx[t] = h1[(b << 8) + t];
  __syncthreads();
  for (int d = 1; d < 256; d <<= 1) {
    u32 add = (t + d < 256) ? sfx[t + d] : 0u;
    __syncthreads();
    sfx[t] += add;
    __syncthreads();
  }
  if (t == 0 && sfx[0] < (u32)PRE) { cstar[b * 32] = 0u; cstar[b * 32 + 1] = sfx[1]; }
  if (sfx[t] >= (u32)PRE && (t == 255 || sfx[t + 1] < (u32)PRE)) {
    cstar[b * 32] = (u32)t;
    cstar[b * 32 + 1] = (t == 255) ? 0u : sfx[t + 1];   // count strictly above c*
  }
}

// phase-2 histogram: 256 fine buckets ((m>>16)&0xFF), filtered to m>>24==c*
__global__ __launch_bounds__(256) void hist2_kernel(const float* __restrict__ cls,
                                                    const u32* __restrict__ cstar,
                                                    u32* __restrict__ h2) {
  __shared__ u32 lh[256];
  int b = blockIdx.y;
  int t = threadIdx.x;
  lh[t] = 0u;
  __syncthreads();
  u32 cs = cstar[b * 32];
  int start = blockIdx.x * EPB;
  int end = min(start + EPB, NPI);
  const float* p = cls + (size_t)b * NPI;
  for (int i = start + t; i < end; i += 256) {
    u32 m = fmono(p[i]);
    if ((m >> 24) == cs) atomicAdd(&lh[(m >> 16) & 0xFFu], 1u);
  }
  __syncthreads();
  if (lh[t]) atomicAdd(&h2[(b << 8) + t], lh[t]);
}

// final 16-bit threshold: thr16 = (c*<<8) | k*, largest k with base+sfx[k] >= PRE
__global__ __launch_bounds__(256) void fine_kernel(const u32* __restrict__ h2,
                                                   const u32* __restrict__ cstar,
                                                   u32* __restrict__ thr) {
  int b = blockIdx.x;
  int t = threadIdx.x;
  __shared__ u32 sfx[256];
  sfx[t] = h2[(b << 8) + t];
  __syncthreads();
  for (int d = 1; d < 256; d <<= 1) {
    u32 add = (t + d < 256) ? sfx[t + d] : 0u;
    __syncthreads();
    sfx[t] += add;
    __syncthreads();
  }
  u32 cs = cstar[b * 32], base = cstar[b * 32 + 1];
  if (t == 0 && base + sfx[0] < (u32)PRE) thr[b * 32] = (cs << 8);
  if (base + sfx[t] >= (u32)PRE && (t == 255 || base + sfx[t + 1] < (u32)PRE))
    thr[b * 32] = (cs << 8) | (u32)t;
}

// wave-aggregated gather: one atomic per wave with >=1 candidate
__global__ void gather_kernel(const float* __restrict__ cls, const u32* __restrict__ thr,
                              u32* __restrict__ ccnt, u64* __restrict__ cand) {
  int tid = blockIdx.x * blockDim.x + threadIdx.x;   // grid exactly covers NTOT
  int b = tid / NPI;
  int r = tid - b * NPI;
  u32 m = fmono(cls[tid]);
  bool pass = (m >> 16) >= thr[b * 32];
  int lane = threadIdx.x & 63;
  int b0 = __shfl(b, 0, 64);
  bool uni = (__ballot(b != b0) == 0ULL);
  u32 pos = 0xffffffffu;
  if (uni) {
    u64 bal = __ballot(pass);
    if (bal) {
      int leader = __ffsll((long long)bal) - 1;
      u32 base = 0;
      if (lane == leader) base = atomicAdd(&ccnt[b * 32], (u32)__popcll(bal));
      base = __shfl(base, leader, 64);
      if (pass) pos = base + (u32)__popcll(bal & ((1ULL << lane) - 1ULL));
    }
  } else if (pass) {
    pos = atomicAdd(&ccnt[b * 32], 1u);
  }
  if (pass && pos < CAP) {
    int a  = r / HW;
    int hw = r - a * HW;
    u32 i  = (u32)(hw * AN + a);   // transposed flat index (h*W + w)*A + a
    cand[(size_t)b * CAP + pos] = ((u64)m << 32) | (u32)(~i);
  }
}

__global__ __launch_bounds__(1024) void sort_transform_kernel(
    const u64* __restrict__ cand, const u32* __restrict__ ccnt,
    const float* __restrict__ bbox, const float* __restrict__ iminfo,
    const float* __restrict__ anch,
    float4* __restrict__ boxes, float* __restrict__ scores, int* __restrict__ valid) {
  __shared__ u64 keys[CAP];   // 32 KB
  int b = blockIdx.x;
  int t = threadIdx.x;
  u32 cnt = ccnt[b * 32];
  if (cnt > CAP) cnt = CAP;
  for (int q = t; q < CAP; q += 1024) keys[q] = (q < (int)cnt) ? cand[(size_t)b * CAP + q] : 0ULL;
  __syncthreads();
  // bitonic sort, descending
  for (u32 k = 2; k <= CAP; k <<= 1) {
    for (u32 j = k >> 1; j > 0; j >>= 1) {
      for (int p = 0; p < CAP / 2 / 1024; ++p) {
        u32 idx = (u32)t + (u32)p * 1024u;           // 0..CAP/2-1
        u32 base = ((idx & ~(j - 1)) << 1) | (idx & (j - 1));
        u32 partner = base + j;
        bool up = ((base & k) == 0);
        u64 A = keys[base], B = keys[partner];
        bool sw = up ? (A < B) : (A > B);
        if (sw) { keys[base] = B; keys[partner] = A; }
      }
      __syncthreads();
    }
  }
  // transform the top PRE
  float im_h = iminfo[b * 3 + 0], im_w = iminfo[b * 3 + 1], im_s = iminfo[b * 3 + 2];
  float wmax = __fsub_rn(im_w, 1.0f), hmax = __fsub_rn(im_h, 1.0f);
  float msz = __fmul_rn(0.0f, im_s);
  const float BCLIP = (float)4.135166556742356;  // log(1000/16)
  for (int q = t; q < PRE; q += 1024) {
    u64 key = keys[q];
    u32 i = ~((u32)key);
    // defensive: pad keys (q >= cnt) decode to i >= NPI -> never dereference
    if (q >= (int)cnt || i >= (u32)NPI) {
      boxes[b * RSTRIDE + q] = make_float4(0.f, 0.f, 0.f, 0.f);
      scores[b * RSTRIDE + q] = 0.f;
      valid[b * RSTRIDE + q] = 0;
      continue;
    }
    float sc = funmono((u32)(key >> 32));
    int a = (int)(i % AN);
    int pp = (int)(i / AN);
    int w = pp % WW;
    int h = pp / WW;
    float sx = (float)(w * 8), sy = (float)(h * 8);
    float ax1 = __fadd_rn(anch[a * 4 + 0], sx);
    float ay1 = __fadd_rn(anch[a * 4 + 1], sy);
    float ax2 = __fadd_rn(anch[a * 4 + 2], sx);
    float ay2 = __fadd_rn(anch[a * 4 + 3], sy);
    float wsA = __fadd_rn(__fsub_rn(ax2, ax1), 1.0f);
    float hsA = __fadd_rn(__fsub_rn(ay2, ay1), 1.0f);
    float cx = __fadd_rn(ax1, __fmul_rn(0.5f, wsA));
    float cy = __fadd_rn(ay1, __fmul_rn(0.5f, hsA));
    const float* dp = bbox + ((size_t)b * (4 * AN) + 4 * a) * HW + (size_t)h * WW + w;
    float dx = dp[0], dy = dp[HW], dwv = dp[2 * HW], dhv = dp[3 * HW];
    dwv = fminf(dwv, BCLIP);
    dhv = fminf(dhv, BCLIP);
    float pcx = __fadd_rn(__fmul_rn(dx, wsA), cx);
    float pcy = __fadd_rn(__fmul_rn(dy, hsA), cy);
    float pw = __fmul_rn((float)exp((double)dwv), wsA);
    float ph = __fmul_rn((float)exp((double)dhv), hsA);
    float hpw = __fmul_rn(0.5f, pw), hph = __fmul_rn(0.5f, ph);
    float x1 = __fsub_rn(pcx, hpw);
    float y1 = __fsub_rn(pcy, hph);
    float x2 = __fsub_rn(__fadd_rn(pcx, hpw), 1.0f);
    float y2 = __fsub_rn(__fadd_rn(pcy, hph), 1.0f);
    x1 = fminf(fmaxf(x1, 0.0f), wmax);
    y1 = fminf(fmaxf(y1, 0.0f), hmax);
    x2 = fminf(fmaxf(x2, 0.0f), wmax);
    y2 = fminf(fmaxf(y2, 0.0f), hmax);
    float ws2 = __fadd_rn(__fsub_rn(x2, x1), 1.0f);
    float hs2 = __fadd_rn(__fsub_rn(y2, y1), 1.0f);
    int v = (ws2 >= msz) && (hs2 >= msz) &&
            (__fadd_rn(x1, __fmul_rn(ws2, 0.5f)) < im_w) &&
            (__fadd_rn(y1, __fmul_rn(hs2, 0.5f)) < im_h);
    boxes[b * RSTRIDE + q] = make_float4(x1, y1, x2, y2);
    scores[b * RSTRIDE + q] = sc;
    valid[b * RSTRIDE + q] = v;
  }
}

__global__ __launch_bounds__(64) void nms_mask_kernel(const float4* __restrict__ boxes,
                                                      u64* __restrict__ mask) {
  int jb = blockIdx.x, ib = blockIdx.y, b = blockIdx.z;
  if (jb < ib) return;   // upper triangle only (j > i needed)
  int t = threadIdx.x;
  __shared__ float4 jbox[64];
  __shared__ float jarea[64];
  int jbase = jb * 64;
  int jcount = min(64, PRE - jbase);
  if (t < jcount) {
    float4 bj = boxes[b * RSTRIDE + jbase + t];
    jbox[t] = bj;
    jarea[t] = areaf(bj);
  }
  __syncthreads();
  int i = ib * 64 + t;
  if (i >= PRE) return;
  float4 bi = boxes[b * RSTRIDE + i];
  float ai = areaf(bi);
  u64 word = 0ULL;
  for (int jj = 0; jj < jcount; ++jj) {
    int j = jbase + jj;
    if (j <= i) continue;
    float4 bj = jbox[jj];
    float iw = fmaxf(__fadd_rn(__fsub_rn(fminf(bi.z, bj.z), fmaxf(bi.x, bj.x)), 1.0f), 0.0f);
    float ih = fmaxf(__fadd_rn(__fsub_rn(fminf(bi.w, bj.w), fmaxf(bi.y, bj.y)), 1.0f), 0.0f);
    float inter = __fmul_rn(iw, ih);
    float denom = __fsub_rn(__fadd_rn(ai, jarea[jj]), inter);
    float iou = inter / denom;
    if (iou > 0.7f) word |= (1ULL << jj);
  }
  mask[((size_t)(b * RSTRIDE) + i) * ROWW + jb] = word;
}

// ---------------- seq NMS v4: v3 + full register budget -----------------
// Lane L holds word (L&31) of rows 2k+(L>>5). R6 postmortem: the tile pair
// (A[32]+Bt[32] = 128 VGPRs) + e[16] + misc needs ~200 VGPRs but the
// compiler's default heuristic capped at 128 -> scratch spills dominated
// (8.8k cyc/chunk vs ~1.5k modeled). __launch_bounds__(64, 1) declares
// 1 wave/EU min occupancy -> full 512-reg budget -> no spills.
__device__ __forceinline__ void nms_chunk(
    int c, const u64* __restrict__ base, u64 (&Rt)[32], u64 (&Pt)[32],
    const u64* __restrict__ vbufLDS, u64& rem, u64& cur,
    u64* __restrict__ kbits_s, int lane, int lw, int hf) {
  // prefetch next chunk's tile (independent of everything below)
  if (c + 1 < NCHUNK) {
    const u64* src = base + (size_t)((c + 1) * 64) * ROWW;
#pragma unroll
    for (int k = 0; k < 32; ++k) Pt[k] = src[(2 * k + hf) * ROWW + lw];
  }
  u64 vb = vbufLDS[c];
  int slo = c, shi = c + 32;   // source lanes holding diag words (even/odd rows)
#pragma unroll
  for (int s = 0; s < 4; ++s) {
    u64 e[16];
#pragma unroll
    for (int j = 0; j < 16; ++j) {
      int ii = s * 16 + j;
      u64 d = (u64)__shfl((long long)Rt[ii >> 1], (ii & 1) ? shi : slo, 64);
      u64 vbm = ((vb >> ii) & 1ULL) ? ~0ULL : 0ULL;
      e[j] = d & vbm;
    }
#pragma unroll
    for (int j = 0; j < 16; ++j) {
      int ii = s * 16 + j;
      cur |= ((cur >> ii) & 1ULL) ? 0ULL : e[j];   // the only serial chain
    }
  }
  u64 keepb = vb & ~cur;
  // fold kept rows into distributed rem (register-only)
#pragma unroll
  for (int k = 0; k < 32; ++k) {
    u64 km = ((keepb >> (2 * k + hf)) & 1ULL) ? ~0ULL : 0ULL;
    rem |= Rt[k] & km;
  }
  if (lane == 0) kbits_s[c] = keepb;
  // seed next chunk's removed word: word c+1 = even-half | odd-half
  int nw = (c + 1) & 31;
  u64 r0 = (u64)__shfl((long long)rem, nw, 64);
  u64 r1 = (u64)__shfl((long long)rem, nw + 32, 64);
  cur = r0 | r1;
}

__global__ __launch_bounds__(64, 1) void seq_nms_kernel(
    const u64* __restrict__ mask, const int* __restrict__ valid,
    const float4* __restrict__ boxes, const float* __restrict__ scores,
    float* __restrict__ out) {
  int b = blockIdx.x;
  int lane = threadIdx.x;
  int lw = lane & 31, hf = lane >> 5;
  __shared__ u64 vbufLDS[NCHUNK];
  __shared__ u64 kbits_s[NCHUNK];
  __shared__ int chunkoff[NCHUNK];
  __shared__ int keeplist[PRE];
  __shared__ int Ksh;

  // preload valid bits: 32 independent loads, then ballots
  {
    int v[NCHUNK];
#pragma unroll
    for (int c = 0; c < NCHUNK; ++c) {
      int q = c * 64 + lane;
      v[c] = (q < PRE) ? valid[b * RSTRIDE + q] : 0;
    }
#pragma unroll
    for (int c = 0; c < NCHUNK; ++c) {
      u64 bl = __ballot(v[c] != 0);
      if (lane == 0) vbufLDS[c] = bl;
    }
  }
  __syncthreads();

  const u64* base = mask + (size_t)b * RSTRIDE * ROWW;
  u64 A[32], Bt[32];
  // load chunk 0 tile
#pragma unroll
  for (int k = 0; k < 32; ++k) A[k] = base[(2 * k + hf) * ROWW + lw];

  u64 rem = 0ULL, cur = 0ULL;
  for (int cc = 0; cc < NCHUNK; cc += 2) {
    nms_chunk(cc,     base, A,  Bt, vbufLDS, rem, cur, kbits_s, lane, lw, hf);
    nms_chunk(cc + 1, base, Bt, A,  vbufLDS, rem, cur, kbits_s, lane, lw, hf);
  }
  __syncthreads();

  // compact keep list: wave prefix-scan of per-chunk popcounts
  {
    int pc = (lane < NCHUNK) ? (int)__popcll(kbits_s[lane]) : 0;
    int inc = pc;
    for (int d = 1; d < 64; d <<= 1) {
      int n = __shfl_up(inc, d, 64);
      if (lane >= d) inc += n;
    }
    if (lane < NCHUNK) chunkoff[lane] = inc - pc;   // exclusive
    if (lane == NCHUNK - 1) Ksh = inc;
  }
  __syncthreads();
  for (int c = 0; c < NCHUNK; ++c) {
    u64 word = kbits_s[c];
    if ((word >> lane) & 1ULL) {
      int rank = (int)__popcll(word & ((1ULL << lane) - 1ULL));
      keeplist[chunkoff[c] + rank] = c * 64 + lane;
    }
  }
  __syncthreads();
  int K = Ksh;

  float* rois = out;
  float* probs = out + (size_t)BN * POST * 5;
  for (int r = lane; r < POST; r += 64) {
    float x1 = 0.f, y1 = 0.f, x2 = 0.f, y2 = 0.f, pr = 0.f;
    if (r < K) {
      int i = keeplist[r];
      float4 bb = boxes[b * RSTRIDE + i];
      x1 = bb.x; y1 = bb.y; x2 = bb.z; y2 = bb.w;
      pr = scores[b * RSTRIDE + i];
    }
    size_t ro = (size_t)(b * POST + r) * 5;
    rois[ro + 0] = (float)b;
    rois[ro + 1] = x1; rois[ro + 2] = y1; rois[ro + 3] = x2; rois[ro + 4] = y2;
    probs[b * POST + r] = pr;
  }
}

extern "C" void kernel_launch(void* const* d_in, const int* in_sizes, int n_in,
                              void* d_out, int out_size, void* d_ws, size_t ws_size,
                              hipStream_t stream) {
  const float* cls    = (const float*)d_in[0];
  const float* bbox   = (const float*)d_in[1];
  const float* iminfo = (const float*)d_in[2];
  const float* anch   = (const float*)d_in[3];
  char* ws = (char*)d_ws;
  u32* h1    = (u32*)(ws + OFF_H1);
  u32* h2    = (u32*)(ws + OFF_H2);
  u32* cstar = (u32*)(ws + OFF_CSTAR);
  u32* ccnt  = (u32*)(ws + OFF_CCNT);
  u32* thr   = (u32*)(ws + OFF_THR);
  u64* cand  = (u64*)(ws + OFF_CAND);
  float4* boxes = (float4*)(ws + OFF_BOX);
  float* scores = (float*)(ws + OFF_SCORE);
  int* valid    = (int*)(ws + OFF_VALID);
  u64* mask     = (u64*)(ws + OFF_MASK);
  float* out = (float*)d_out;

  zero_kernel<<<(ZERO_WORDS + 255) / 256, 256, 0, stream>>>((u32*)ws, ZERO_WORDS);
  hist1_kernel<<<dim3(HBLK, BN), 256, 0, stream>>>(cls, h1);
  coarse_kernel<<<BN, 256, 0, stream>>>(h1, cstar);
  hist2_kernel<<<dim3(HBLK, BN), 256, 0, stream>>>(cls, cstar, h2);
  fine_kernel<<<BN, 256, 0, stream>>>(h2, cstar, thr);
  gather_kernel<<<NTOT / 256, 256, 0, stream>>>(cls, thr, ccnt, cand);
  sort_transform_kernel<<<BN, 1024, 0, stream>>>(cand, ccnt, bbox, iminfo, anch,
                                                 boxes, scores, valid);
  nms_mask_kernel<<<dim3(32, 32, BN), 64, 0, stream>>>(boxes, mask);
  seq_nms_kernel<<<BN, 64, 0, stream>>>(mask, valid, boxes, scores, out);
}